// Round 1
// baseline (3050.616 us; speedup 1.0000x reference)
//
#include <hip/hip_runtime.h>
#include <hip/hip_bf16.h>

#define GN 16384
#define GH 16
#define GK 16
#define GL 4

// knn tiling
#define KTC 256   // columns per LDS tile
#define KRPB 32   // rows per block
#define KTPR 8    // threads per row
#define KPAD 20   // floats per column in LDS (16 data + 1 sq + 3 pad) -> conflict-free

// workspace float-offsets
#define OFF_H0   0
#define OFF_IDX  (5*GN*GH)              /* ints, GN*GK */
#define OFF_CONV (OFF_IDX + GN*GK)
#define OFF_XF    OFF_CONV
#define OFF_EMBW (OFF_XF + GN*3)
#define OFF_EMBB (OFF_EMBW + 3*GH)
#define OFF_W1   (OFF_EMBB + GH)
#define OFF_B1   (OFF_W1 + GL*2*GH*GH)
#define OFF_W2   (OFF_B1 + GL*GH)
#define OFF_B2   (OFF_W2 + GL*GH*GH)
#define OFF_OW   (OFF_B2 + GL*GH)
#define OFF_OB   (OFF_OW + GL*GH*3)
#define OFF_FLAG (OFF_OB + 4)

// ---------------------------------------------------------------------------
// dtype detection: if inputs are f32, the low 16 bits of each word are random
// mantissa bits -> interpreted as bf16 they are mostly out of [1e-4, 50).
// If inputs are bf16, even-position u16s are genuine N(0,1) values -> in range.
__global__ void detect_kernel(const unsigned short* __restrict__ raw,
                              int* __restrict__ flag)
{
    if (threadIdx.x == 0 && blockIdx.x == 0) {
        int cnt = 0;
        for (int i = 0; i < 64; ++i) {
            unsigned int bits = ((unsigned int)raw[2*i]) << 16;
            float v = __uint_as_float(bits);
            float a = fabsf(v);
            if (a > 1e-4f && a < 50.f) ++cnt;
        }
        *flag = (cnt >= 32) ? 1 : 0;   // 1 = inputs are bf16
    }
}

__global__ void convert_kernel(const void* __restrict__ src,
                               float* __restrict__ dst, int n,
                               const int* __restrict__ flag)
{
    int i = blockIdx.x * 256 + threadIdx.x;
    if (i >= n) return;
    if (*flag)
        dst[i] = __bfloat162float(((const __hip_bfloat16*)src)[i]);
    else
        dst[i] = ((const float*)src)[i];
}

// ---------------------------------------------------------------------------
__global__ __launch_bounds__(256) void embed_kernel(
    const float* __restrict__ xf, const float* __restrict__ W,
    const float* __restrict__ b, float* __restrict__ h0)
{
    int i = blockIdx.x * 256 + threadIdx.x;
    float x0 = xf[i*3+0], x1 = xf[i*3+1], x2 = xf[i*3+2];
#pragma unroll
    for (int c = 0; c < GH; ++c) {
        float t = b[c];
        t = fmaf(x0, W[0*GH+c], t);
        t = fmaf(x1, W[1*GH+c], t);
        t = fmaf(x2, W[2*GH+c], t);
        h0[i*GH+c] = fmaxf(t, 0.f);
    }
}

// ---------------------------------------------------------------------------
__global__ __launch_bounds__(256) void knn_kernel(
    const float* __restrict__ h, int* __restrict__ idxout)
{
    __shared__ float tile[KTC * KPAD];   // 20 KB
    const int tid = threadIdx.x;
    const int r = tid >> 3;
    const int q = tid & 7;
    const int row = blockIdx.x * KRPB + r;

    float hi[GH];
    {
        const float4* hv = (const float4*)(h + row * GH);
        float4 A = hv[0], B = hv[1], C = hv[2], D = hv[3];
        hi[0]=A.x; hi[1]=A.y; hi[2]=A.z; hi[3]=A.w;
        hi[4]=B.x; hi[5]=B.y; hi[6]=B.z; hi[7]=B.w;
        hi[8]=C.x; hi[9]=C.y; hi[10]=C.z; hi[11]=C.w;
        hi[12]=D.x; hi[13]=D.y; hi[14]=D.z; hi[15]=D.w;
    }
    float sqi = 0.f;
#pragma unroll
    for (int c = 0; c < GH; ++c) sqi = fmaf(hi[c], hi[c], sqi);

    float topd[GK];
    int   topi[GK];
#pragma unroll
    for (int s = 0; s < GK; ++s) { topd[s] = __builtin_inff(); topi[s] = -1; }
    float maxd = __builtin_inff();
    int maxslot = 0;

    for (int base = 0; base < GN; base += KTC) {
        __syncthreads();
        {   // stage one column per thread (coalesced, conflict-free writes)
            const int col = base + tid;
            const float4* src = (const float4*)(h + col * GH);
            float4 A = src[0], B = src[1], C = src[2], D = src[3];
            float* dst = &tile[tid * KPAD];
            *(float4*)(dst + 0)  = A;
            *(float4*)(dst + 4)  = B;
            *(float4*)(dst + 8)  = C;
            *(float4*)(dst + 12) = D;
            float sq = 0.f;
            sq = fmaf(A.x,A.x,sq); sq = fmaf(A.y,A.y,sq); sq = fmaf(A.z,A.z,sq); sq = fmaf(A.w,A.w,sq);
            sq = fmaf(B.x,B.x,sq); sq = fmaf(B.y,B.y,sq); sq = fmaf(B.z,B.z,sq); sq = fmaf(B.w,B.w,sq);
            sq = fmaf(C.x,C.x,sq); sq = fmaf(C.y,C.y,sq); sq = fmaf(C.z,C.z,sq); sq = fmaf(C.w,C.w,sq);
            sq = fmaf(D.x,D.x,sq); sq = fmaf(D.y,D.y,sq); sq = fmaf(D.z,D.z,sq); sq = fmaf(D.w,D.w,sq);
            dst[16] = sq;
        }
        __syncthreads();
#pragma unroll 4
        for (int m = 0; m < KTC / KTPR; ++m) {
            const int jl = m * KTPR + q;
            const float* hj = &tile[jl * KPAD];
            float4 A = *(const float4*)(hj + 0);
            float4 B = *(const float4*)(hj + 4);
            float4 C = *(const float4*)(hj + 8);
            float4 D = *(const float4*)(hj + 12);
            const float sqj = hj[16];
            float d0 = hi[0]*A.x;
            float d1 = hi[1]*A.y;
            d0 = fmaf(hi[2],  A.z, d0);  d1 = fmaf(hi[3],  A.w, d1);
            d0 = fmaf(hi[4],  B.x, d0);  d1 = fmaf(hi[5],  B.y, d1);
            d0 = fmaf(hi[6],  B.z, d0);  d1 = fmaf(hi[7],  B.w, d1);
            d0 = fmaf(hi[8],  C.x, d0);  d1 = fmaf(hi[9],  C.y, d1);
            d0 = fmaf(hi[10], C.z, d0);  d1 = fmaf(hi[11], C.w, d1);
            d0 = fmaf(hi[12], D.x, d0);  d1 = fmaf(hi[13], D.y, d1);
            d0 = fmaf(hi[14], D.z, d0);  d1 = fmaf(hi[15], D.w, d1);
            const float dot = d0 + d1;
            float dcand = fmaf(-2.f, dot, sqi + sqj);
            const int j = base + jl;
            if (j == row) dcand = __builtin_inff();
            if (dcand < maxd) {
                // replace current max slot, rescan for new max (static indices)
#pragma unroll
                for (int s = 0; s < GK; ++s) {
                    const bool cs = (s == maxslot);
                    topd[s] = cs ? dcand : topd[s];
                    topi[s] = cs ? j : topi[s];
                }
                maxd = topd[0]; maxslot = 0;
#pragma unroll
                for (int s = 1; s < GK; ++s) {
                    const bool cs = (topd[s] >= maxd);
                    maxd   = cs ? topd[s] : maxd;
                    maxslot = cs ? s : maxslot;
                }
            }
        }
    }

    // merge the 8 per-thread top-16 lists of each row (registers + shuffles)
    for (int t = 0; t < GK; ++t) {
        float md = topd[0]; int mj = topi[0]; int ms = 0;
#pragma unroll
        for (int s = 1; s < GK; ++s) {
            const bool cs = (topd[s] < md) || (topd[s] == md && topi[s] < mj);
            md = cs ? topd[s] : md;
            mj = cs ? topi[s] : mj;
            ms = cs ? s : ms;
        }
        float rd = md; int rj = mj;
#pragma unroll
        for (int mm = 1; mm <= 4; mm <<= 1) {
            const float od = __shfl_xor(rd, mm, 8);
            const int   oj = __shfl_xor(rj, mm, 8);
            const bool cs = (od < rd) || (od == rd && oj < rj);
            rd = cs ? od : rd;
            rj = cs ? oj : rj;
        }
        if (q == 0) idxout[row * GK + t] = rj;
        if (rd == md && rj == mj) {
#pragma unroll
            for (int s = 0; s < GK; ++s) if (s == ms) topd[s] = __builtin_inff();
        }
    }
}

// ---------------------------------------------------------------------------
__global__ __launch_bounds__(256) void edgeconv_kernel(
    const float* __restrict__ hin, const int* __restrict__ idx,
    const float* __restrict__ W1, const float* __restrict__ b1,
    const float* __restrict__ W2, const float* __restrict__ b2,
    float* __restrict__ hout)
{
    __shared__ float sW1[2*GH*GH], sW2[GH*GH], sb1[GH], sb2[GH];
    const int tid = threadIdx.x;
    for (int t = tid; t < 2*GH*GH; t += 256) sW1[t] = W1[t];
    for (int t = tid; t < GH*GH;  t += 256) sW2[t] = W2[t];
    if (tid < GH) { sb1[tid] = b1[tid]; sb2[tid] = b2[tid]; }
    __syncthreads();

    const int t4 = tid & 3;
    const int i = blockIdx.x * 64 + (tid >> 2);

    float hi[GH];
    {
        const float4* hv = (const float4*)(hin + i * GH);
        float4 A = hv[0], B = hv[1], C = hv[2], D = hv[3];
        hi[0]=A.x; hi[1]=A.y; hi[2]=A.z; hi[3]=A.w;
        hi[4]=B.x; hi[5]=B.y; hi[6]=B.z; hi[7]=B.w;
        hi[8]=C.x; hi[9]=C.y; hi[10]=C.z; hi[11]=C.w;
        hi[12]=D.x; hi[13]=D.y; hi[14]=D.z; hi[15]=D.w;
    }
    float ci[GH];
#pragma unroll
    for (int c = 0; c < GH; ++c) {
        float s = sb1[c];
#pragma unroll
        for (int d = 0; d < GH; ++d) s = fmaf(hi[d], sW1[d*GH+c], s);
        ci[c] = s;
    }
    float acc[GH];
#pragma unroll
    for (int c = 0; c < GH; ++c) acc[c] = 0.f;

    const int4 jj = *(const int4*)(idx + i*GK + t4*4);
    const int js[4] = { jj.x, jj.y, jj.z, jj.w };
#pragma unroll
    for (int nn = 0; nn < 4; ++nn) {
        const int j = js[nn];
        float dj[GH];
        {
            const float4* hv = (const float4*)(hin + j * GH);
            float4 A = hv[0], B = hv[1], C = hv[2], D = hv[3];
            dj[0]=A.x-hi[0]; dj[1]=A.y-hi[1]; dj[2]=A.z-hi[2]; dj[3]=A.w-hi[3];
            dj[4]=B.x-hi[4]; dj[5]=B.y-hi[5]; dj[6]=B.z-hi[6]; dj[7]=B.w-hi[7];
            dj[8]=C.x-hi[8]; dj[9]=C.y-hi[9]; dj[10]=C.z-hi[10]; dj[11]=C.w-hi[11];
            dj[12]=D.x-hi[12]; dj[13]=D.y-hi[13]; dj[14]=D.z-hi[14]; dj[15]=D.w-hi[15];
        }
        float msg[GH];
#pragma unroll
        for (int c = 0; c < GH; ++c) {
            float s = ci[c];
#pragma unroll
            for (int d = 0; d < GH; ++d) s = fmaf(dj[d], sW1[(GH+d)*GH+c], s);
            msg[c] = fmaxf(s, 0.f);
        }
#pragma unroll
        for (int c2 = 0; c2 < GH; ++c2) {
            float s = acc[c2];
#pragma unroll
            for (int c = 0; c < GH; ++c) s = fmaf(msg[c], sW2[c*GH+c2], s);
            acc[c2] = s;
        }
    }
    // reduce partial sums across the 4 lanes of this point, then mean + bias
#pragma unroll
    for (int c = 0; c < GH; ++c) {
        acc[c] += __shfl_xor(acc[c], 1);
        acc[c] += __shfl_xor(acc[c], 2);
    }
    if (t4 == 0) {
#pragma unroll
        for (int c = 0; c < GH; ++c)
            hout[i*GH+c] = acc[c] * (1.f/16.f) + sb2[c];
    }
}

// ---------------------------------------------------------------------------
__global__ __launch_bounds__(256) void out_kernel(
    const float* __restrict__ hbase, const float* __restrict__ W,
    const float* __restrict__ b, void* __restrict__ out,
    const int* __restrict__ flag)
{
    int i = blockIdx.x * 256 + threadIdx.x;
    float a0 = b[0], a1 = b[1], a2 = b[2];
#pragma unroll
    for (int l = 0; l < GL; ++l) {
        const float* hp = hbase + l * GN * GH + i * GH;
#pragma unroll
        for (int c = 0; c < GH; ++c) {
            const float v = hp[c];
            const float* wr = W + (l * GH + c) * 3;
            a0 = fmaf(v, wr[0], a0);
            a1 = fmaf(v, wr[1], a1);
            a2 = fmaf(v, wr[2], a2);
        }
    }
    if (*flag) {
        __hip_bfloat16* o = (__hip_bfloat16*)out;
        o[i*3+0] = __float2bfloat16(a0);
        o[i*3+1] = __float2bfloat16(a1);
        o[i*3+2] = __float2bfloat16(a2);
    } else {
        float* o = (float*)out;
        o[i*3+0] = a0; o[i*3+1] = a1; o[i*3+2] = a2;
    }
}

// ---------------------------------------------------------------------------
extern "C" void kernel_launch(void* const* d_in, const int* in_sizes, int n_in,
                              void* d_out, int out_size, void* d_ws, size_t ws_size,
                              hipStream_t stream)
{
    float* wsf = (float*)d_ws;
    int* idxb  = (int*)(wsf + OFF_IDX);
    int* flag  = (int*)(wsf + OFF_FLAG);

    detect_kernel<<<1, 64, 0, stream>>>((const unsigned short*)d_in[0], flag);

    const int segsrc[9] = {0,1,2,3,4,5,6,7,8};
    const int segoff[9] = {OFF_XF, OFF_EMBW, OFF_EMBB, OFF_W1, OFF_B1,
                           OFF_W2, OFF_B2, OFF_OW, OFF_OB};
    const int segn[9]   = {GN*3, 3*GH, GH, GL*2*GH*GH, GL*GH,
                           GL*GH*GH, GL*GH, GL*GH*3, 3};
    for (int s = 0; s < 9; ++s)
        convert_kernel<<<(segn[s] + 255)/256, 256, 0, stream>>>(
            d_in[segsrc[s]], wsf + segoff[s], segn[s], flag);

    embed_kernel<<<GN/256, 256, 0, stream>>>(
        wsf + OFF_XF, wsf + OFF_EMBW, wsf + OFF_EMBB, wsf + OFF_H0);

    for (int l = 0; l < GL; ++l) {
        const float* hin = wsf + OFF_H0 + l*GN*GH;
        float* hout      = wsf + OFF_H0 + (l+1)*GN*GH;
        knn_kernel<<<GN/KRPB, 256, 0, stream>>>(hin, idxb);
        edgeconv_kernel<<<GN/64, 256, 0, stream>>>(hin, idxb,
            wsf + OFF_W1 + l*2*GH*GH, wsf + OFF_B1 + l*GH,
            wsf + OFF_W2 + l*GH*GH,  wsf + OFF_B2 + l*GH, hout);
    }

    out_kernel<<<GN/256, 256, 0, stream>>>(
        wsf + OFF_H0 + GN*GH, wsf + OFF_OW, wsf + OFF_OB, d_out, flag);
}

// Round 2
// 2709.090 us; speedup vs baseline: 1.1261x; 1.1261x over previous
//
#include <hip/hip_runtime.h>
#include <hip/hip_bf16.h>

#define GN 16384
#define GH 16
#define GK 16
#define GL 4
#define HPS 20            // padded h row: 16 features + sq + 3 pad (80 B, 16B-aligned)

// knn2 params
#define RPB 32            // rows per block
#define NTHR 1024         // 16 waves; 32 scan-slots (wave x half) x 512 cols
#define CAP 160           // collect buffer capacity per row (5 slots x 32 lanes)
#define BSTR 161          // buffer row stride (floats)
#define SSTR 264          // phase-1 sample-merge row stride (16B-aligned, padded)
#define NSAMP 128         // samples per scan-slot (512/4)

#define INFF __builtin_inff()

// workspace float-offsets
#define OFF_H     0
#define OFF_IDX   (5*GN*HPS)
#define OFF_FLAGS (OFF_IDX + GN*GK)
#define OFF_XF    (OFF_FLAGS + GN)
#define OFF_EMBW  (OFF_XF + GN*3)
#define OFF_EMBB  (OFF_EMBW + 3*GH)
#define OFF_W1    (OFF_EMBB + GH)
#define OFF_B1    (OFF_W1 + GL*2*GH*GH)
#define OFF_W2    (OFF_B1 + GL*GH)
#define OFF_B2    (OFF_W2 + GL*GH*GH)
#define OFF_OW    (OFF_B2 + GL*GH)
#define OFF_OB    (OFF_OW + GL*GH*3)
#define OFF_DFLAG (OFF_OB + 4)

// ---------------------------------------------------------------------------
__global__ void detect_kernel(const unsigned short* __restrict__ raw,
                              int* __restrict__ flag)
{
    if (threadIdx.x == 0 && blockIdx.x == 0) {
        int cnt = 0;
        for (int i = 0; i < 64; ++i) {
            unsigned int bits = ((unsigned int)raw[2*i]) << 16;
            float v = __uint_as_float(bits);
            float a = fabsf(v);
            if (a > 1e-4f && a < 50.f) ++cnt;
        }
        *flag = (cnt >= 32) ? 1 : 0;   // 1 = inputs are bf16
    }
}

__global__ void convert_kernel(const void* __restrict__ src,
                               float* __restrict__ dst, int n,
                               const int* __restrict__ flag)
{
    int i = blockIdx.x * 256 + threadIdx.x;
    if (i >= n) return;
    if (*flag)
        dst[i] = __bfloat162float(((const __hip_bfloat16*)src)[i]);
    else
        dst[i] = ((const float*)src)[i];
}

// ---------------------------------------------------------------------------
__device__ __forceinline__ float distf(const float hi[16], float sqi,
                                       const float* __restrict__ hj)
{
    float4 A = *(const float4*)(hj + 0);
    float4 B = *(const float4*)(hj + 4);
    float4 C = *(const float4*)(hj + 8);
    float4 D = *(const float4*)(hj + 12);
    float sqj = hj[16];
    float d0 = hi[0]*A.x;
    float d1 = hi[1]*A.y;
    d0 = fmaf(hi[2],  A.z, d0);  d1 = fmaf(hi[3],  A.w, d1);
    d0 = fmaf(hi[4],  B.x, d0);  d1 = fmaf(hi[5],  B.y, d1);
    d0 = fmaf(hi[6],  B.z, d0);  d1 = fmaf(hi[7],  B.w, d1);
    d0 = fmaf(hi[8],  C.x, d0);  d1 = fmaf(hi[9],  C.y, d1);
    d0 = fmaf(hi[10], C.z, d0);  d1 = fmaf(hi[11], C.w, d1);
    d0 = fmaf(hi[12], D.x, d0);  d1 = fmaf(hi[13], D.y, d1);
    d0 = fmaf(hi[14], D.z, d0);  d1 = fmaf(hi[15], D.w, d1);
    return fmaf(-2.f, d0 + d1, sqi + sqj);
}

#define LOAD_HI(ptr)                                                        \
    float hi[16]; float sqi;                                                \
    {                                                                       \
        const float* _hr = (ptr);                                           \
        float4 A = *(const float4*)(_hr + 0);                               \
        float4 B = *(const float4*)(_hr + 4);                               \
        float4 C = *(const float4*)(_hr + 8);                               \
        float4 D = *(const float4*)(_hr + 12);                              \
        hi[0]=A.x; hi[1]=A.y; hi[2]=A.z; hi[3]=A.w;                         \
        hi[4]=B.x; hi[5]=B.y; hi[6]=B.z; hi[7]=B.w;                         \
        hi[8]=C.x; hi[9]=C.y; hi[10]=C.z; hi[11]=C.w;                       \
        hi[12]=D.x; hi[13]=D.y; hi[14]=D.z; hi[15]=D.w;                     \
        sqi = _hr[16];                                                      \
    }

// ---------------------------------------------------------------------------
__global__ __launch_bounds__(256) void embed_kernel(
    const float* __restrict__ xf, const float* __restrict__ W,
    const float* __restrict__ b, float* __restrict__ h0)
{
    int i = blockIdx.x * 256 + threadIdx.x;
    float x0 = xf[i*3+0], x1 = xf[i*3+1], x2 = xf[i*3+2];
    float* orow = h0 + i * HPS;
    float sq = 0.f;
#pragma unroll
    for (int c = 0; c < GH; ++c) {
        float t = b[c];
        t = fmaf(x0, W[0*GH+c], t);
        t = fmaf(x1, W[1*GH+c], t);
        t = fmaf(x2, W[2*GH+c], t);
        t = fmaxf(t, 0.f);
        orow[c] = t;
        sq = fmaf(t, t, sq);
    }
    orow[16] = sq;
}

// ---------------------------------------------------------------------------
// Exact kNN via 2-phase threshold-collect.
__global__ __launch_bounds__(NTHR, 4) void knn2_kernel(
    const float* __restrict__ hp, int* __restrict__ idxout,
    int* __restrict__ flags)
{
    __shared__ float lds[2*RPB*BSTR + 2*RPB];   // 41.5 KB
    float*    bufd = lds;
    int*      bufj = (int*)(lds + RPB*BSTR);
    unsigned* cnt  = (unsigned*)(lds + 2*RPB*BSTR);
    float*    tau  = lds + 2*RPB*BSTR + RPB;

    const int tid  = threadIdx.x;
    const int r    = tid & 31;          // row-in-block for scan mapping
    const int slot = tid >> 5;          // 0..31 scan slot (wave*2 + half)
    const int row  = blockIdx.x * RPB + r;
    const int colbase = slot << 9;      // *512

    LOAD_HI(hp + row * HPS);

    // ---- phase 1: sample every 4th column in this slot's range; per-lane top-8 values
    float t8[8];
#pragma unroll
    for (int s = 0; s < 8; ++s) t8[s] = INFF;
    float mx = INFF; int mxs = 0;
    for (int s = 0; s < NSAMP; ++s) {
        int j = colbase + (s << 2);
        float d = distf(hi, sqi, hp + j * HPS);
        if (j == row) d = INFF;
        if (d < mx) {
#pragma unroll
            for (int q = 0; q < 8; ++q) { bool cs = (q == mxs); t8[q] = cs ? d : t8[q]; }
            mx = t8[0]; mxs = 0;
#pragma unroll
            for (int q = 1; q < 8; ++q) { bool cs = (t8[q] >= mx); mx = cs ? t8[q] : mx; mxs = cs ? q : mxs; }
        }
    }
    {   // stash per-lane top-8 (values only) for the row merge; overlays buffer region
        *(float4*)(lds + r*SSTR + slot*8)     = make_float4(t8[0], t8[1], t8[2], t8[3]);
        *(float4*)(lds + r*SSTR + slot*8 + 4) = make_float4(t8[4], t8[5], t8[6], t8[7]);
    }
    __syncthreads();

    // ---- phase 1b: per-row merge (32 lanes/row): tau = 16th smallest sample distance
    const int mr = tid >> 5, g = tid & 31;
    float s8[8];
    {
        float4 u0 = *(const float4*)(lds + mr*SSTR + g*8);
        float4 u1 = *(const float4*)(lds + mr*SSTR + g*8 + 4);
        s8[0]=u0.x; s8[1]=u0.y; s8[2]=u0.z; s8[3]=u0.w;
        s8[4]=u1.x; s8[5]=u1.y; s8[6]=u1.z; s8[7]=u1.w;
    }
    float tval = INFF;
#pragma unroll
    for (int k = 0; k < 16; ++k) {
        float md = s8[0]; int ms = 0;
#pragma unroll
        for (int q = 1; q < 8; ++q) { bool cs = (s8[q] < md); md = cs ? s8[q] : md; ms = cs ? q : ms; }
        float rv = md; int rl = g;
#pragma unroll
        for (int m = 1; m <= 16; m <<= 1) {
            float ov = __shfl_xor(rv, m, 32);
            int   ol = __shfl_xor(rl, m, 32);
            bool cs = (ov < rv) || (ov == rv && ol < rl);
            rv = cs ? ov : rv; rl = cs ? ol : rl;
        }
        if (rl == g) {
#pragma unroll
            for (int q = 0; q < 8; ++q) if (q == ms) s8[q] = INFF;
        }
        tval = rv;
    }
    if (g == 0) tau[mr] = tval;
    if (tid < RPB) cnt[tid] = 0;
    __syncthreads();   // tau/cnt ready; smp reads done before buffer overwrite

    // ---- phase 2: full scan, append d <= tau to per-row buffer.
    // count >= 16 guaranteed: the 16 sample distances <= tau re-qualify here.
    const float taur  = tau[r];
    const int rowoff = r * BSTR;
#pragma unroll 2
    for (int t = 0; t < 512; ++t) {
        int j = colbase + t;
        float d = distf(hi, sqi, hp + j * HPS);
        if (j == row) d = INFF;
        if (d <= taur) {
            unsigned pos = atomicAdd(&cnt[r], 1u);
            if (pos < CAP) { bufd[rowoff + pos] = d; bufj[rowoff + pos] = j; }
        }
    }
    __syncthreads();

    // ---- phase 3: exact top-16 of buffer per row (32 lanes/row), (d,j) tie-break
    const unsigned c   = cnt[mr];
    const unsigned lim = c < CAP ? c : CAP;
    float sd[5]; int sj[5];
#pragma unroll
    for (int e = 0; e < 5; ++e) {
        unsigned p = (unsigned)g + 32u*e;
        bool v = p < lim;
        sd[e] = v ? bufd[mr*BSTR + p] : INFF;
        sj[e] = v ? bufj[mr*BSTR + p] : 0x7fffffff;
    }
    const int rowg = blockIdx.x * RPB + mr;
#pragma unroll
    for (int k = 0; k < GK; ++k) {
        float md = sd[0]; int mj = sj[0]; int ms = 0;
#pragma unroll
        for (int e = 1; e < 5; ++e) {
            bool cs = (sd[e] < md) || (sd[e] == md && sj[e] < mj);
            md = cs ? sd[e] : md; mj = cs ? sj[e] : mj; ms = cs ? e : ms;
        }
        float rd = md; int rj = mj;
#pragma unroll
        for (int m = 1; m <= 16; m <<= 1) {
            float od = __shfl_xor(rd, m, 32);
            int   oj = __shfl_xor(rj, m, 32);
            bool cs = (od < rd) || (od == rd && oj < rj);
            rd = cs ? od : rd; rj = cs ? oj : rj;
        }
        if (g == 0) idxout[rowg*GK + k] = rj;
        if (rd == md && rj == mj) {
#pragma unroll
            for (int e = 0; e < 5; ++e) if (e == ms) { sd[e] = INFF; sj[e] = 0x7fffffff; }
        }
    }
    if (g == 0) flags[rowg] = (c > CAP || c < 16u) ? 1 : 0;
}

// ---------------------------------------------------------------------------
// Exact full-scan fallback for rows whose buffer overflowed (P ~ 3e-5/row).
__global__ __launch_bounds__(64) void rescue_kernel(
    const float* __restrict__ hp, const int* __restrict__ flags,
    int* __restrict__ idxout)
{
    const int lane = threadIdx.x;
    const int r0 = blockIdx.x * RPB;
    int f = (lane < RPB) ? flags[r0 + lane] : 0;
    if (__ballot(f != 0) == 0ull) return;
    for (int rr = 0; rr < RPB; ++rr) {
        if (flags[r0 + rr] == 0) continue;
        const int row = r0 + rr;
        LOAD_HI(hp + row * HPS);
        float topd[GK]; int topi[GK];
#pragma unroll
        for (int s = 0; s < GK; ++s) { topd[s] = INFF; topi[s] = -1; }
        float mx = INFF; int mxs = 0;
        for (int s = 0; s < GN/64; ++s) {
            int j = lane + (s << 6);
            float d = distf(hi, sqi, hp + j * HPS);
            if (j == row) d = INFF;
            if (d < mx) {
#pragma unroll
                for (int q = 0; q < GK; ++q) { bool cs = (q == mxs); topd[q] = cs ? d : topd[q]; topi[q] = cs ? j : topi[q]; }
                mx = topd[0]; mxs = 0;
#pragma unroll
                for (int q = 1; q < GK; ++q) { bool cs = (topd[q] >= mx); mx = cs ? topd[q] : mx; mxs = cs ? q : mxs; }
            }
        }
#pragma unroll
        for (int t = 0; t < GK; ++t) {
            float md = topd[0]; int mj = topi[0]; int ms = 0;
#pragma unroll
            for (int q = 1; q < GK; ++q) {
                bool cs = (topd[q] < md) || (topd[q] == md && topi[q] < mj);
                md = cs ? topd[q] : md; mj = cs ? topi[q] : mj; ms = cs ? q : ms;
            }
            float rd = md; int rj = mj;
#pragma unroll
            for (int m = 1; m <= 32; m <<= 1) {
                float od = __shfl_xor(rd, m, 64);
                int   oj = __shfl_xor(rj, m, 64);
                bool cs = (od < rd) || (od == rd && oj < rj);
                rd = cs ? od : rd; rj = cs ? oj : rj;
            }
            if (lane == 0) idxout[row*GK + t] = rj;
            if (rd == md && rj == mj) {
#pragma unroll
                for (int q = 0; q < GK; ++q) if (q == ms) { topd[q] = INFF; topi[q] = 0x7fffffff; }
            }
        }
    }
}

// ---------------------------------------------------------------------------
__global__ __launch_bounds__(256) void edgeconv_kernel(
    const float* __restrict__ hin, const int* __restrict__ idx,
    const float* __restrict__ W1, const float* __restrict__ b1,
    const float* __restrict__ W2, const float* __restrict__ b2,
    float* __restrict__ hout)
{
    __shared__ float sW1[2*GH*GH], sW2[GH*GH], sb1[GH], sb2[GH];
    const int tid = threadIdx.x;
    for (int t = tid; t < 2*GH*GH; t += 256) sW1[t] = W1[t];
    for (int t = tid; t < GH*GH;  t += 256) sW2[t] = W2[t];
    if (tid < GH) { sb1[tid] = b1[tid]; sb2[tid] = b2[tid]; }
    __syncthreads();

    const int t4 = tid & 3;
    const int i = blockIdx.x * 64 + (tid >> 2);

    LOAD_HI(hin + i * HPS);
    (void)sqi;
    float ci[GH];
#pragma unroll
    for (int c = 0; c < GH; ++c) {
        float s = sb1[c];
#pragma unroll
        for (int d = 0; d < GH; ++d) s = fmaf(hi[d], sW1[d*GH+c], s);
        ci[c] = s;
    }
    float acc[GH];
#pragma unroll
    for (int c = 0; c < GH; ++c) acc[c] = 0.f;

    const int4 jj = *(const int4*)(idx + i*GK + t4*4);
    const int js[4] = { jj.x, jj.y, jj.z, jj.w };
#pragma unroll
    for (int nn = 0; nn < 4; ++nn) {
        const int j = js[nn];
        float dj[GH];
        {
            const float* hv = hin + j * HPS;
            float4 A = *(const float4*)(hv + 0);
            float4 B = *(const float4*)(hv + 4);
            float4 C = *(const float4*)(hv + 8);
            float4 D = *(const float4*)(hv + 12);
            dj[0]=A.x-hi[0]; dj[1]=A.y-hi[1]; dj[2]=A.z-hi[2]; dj[3]=A.w-hi[3];
            dj[4]=B.x-hi[4]; dj[5]=B.y-hi[5]; dj[6]=B.z-hi[6]; dj[7]=B.w-hi[7];
            dj[8]=C.x-hi[8]; dj[9]=C.y-hi[9]; dj[10]=C.z-hi[10]; dj[11]=C.w-hi[11];
            dj[12]=D.x-hi[12]; dj[13]=D.y-hi[13]; dj[14]=D.z-hi[14]; dj[15]=D.w-hi[15];
        }
        float msg[GH];
#pragma unroll
        for (int c = 0; c < GH; ++c) {
            float s = ci[c];
#pragma unroll
            for (int d = 0; d < GH; ++d) s = fmaf(dj[d], sW1[(GH+d)*GH+c], s);
            msg[c] = fmaxf(s, 0.f);
        }
#pragma unroll
        for (int c2 = 0; c2 < GH; ++c2) {
            float s = acc[c2];
#pragma unroll
            for (int c = 0; c < GH; ++c) s = fmaf(msg[c], sW2[c*GH+c2], s);
            acc[c2] = s;
        }
    }
#pragma unroll
    for (int c = 0; c < GH; ++c) {
        acc[c] += __shfl_xor(acc[c], 1);
        acc[c] += __shfl_xor(acc[c], 2);
    }
    if (t4 == 0) {
        float* orow = hout + i * HPS;
        float sq = 0.f;
#pragma unroll
        for (int c = 0; c < GH; ++c) {
            float v = acc[c] * (1.f/16.f) + sb2[c];
            orow[c] = v;
            sq = fmaf(v, v, sq);
        }
        orow[16] = sq;
    }
}

// ---------------------------------------------------------------------------
__global__ __launch_bounds__(256) void out_kernel(
    const float* __restrict__ hbase, const float* __restrict__ W,
    const float* __restrict__ b, void* __restrict__ out,
    const int* __restrict__ flag)
{
    int i = blockIdx.x * 256 + threadIdx.x;
    float a0 = b[0], a1 = b[1], a2 = b[2];
#pragma unroll
    for (int l = 0; l < GL; ++l) {
        const float* hp = hbase + l * GN * HPS + i * HPS;
#pragma unroll
        for (int c = 0; c < GH; ++c) {
            const float v = hp[c];
            const float* wr = W + (l * GH + c) * 3;
            a0 = fmaf(v, wr[0], a0);
            a1 = fmaf(v, wr[1], a1);
            a2 = fmaf(v, wr[2], a2);
        }
    }
    if (*flag) {
        __hip_bfloat16* o = (__hip_bfloat16*)out;
        o[i*3+0] = __float2bfloat16(a0);
        o[i*3+1] = __float2bfloat16(a1);
        o[i*3+2] = __float2bfloat16(a2);
    } else {
        float* o = (float*)out;
        o[i*3+0] = a0; o[i*3+1] = a1; o[i*3+2] = a2;
    }
}

// ---------------------------------------------------------------------------
extern "C" void kernel_launch(void* const* d_in, const int* in_sizes, int n_in,
                              void* d_out, int out_size, void* d_ws, size_t ws_size,
                              hipStream_t stream)
{
    float* wsf  = (float*)d_ws;
    int* idxb   = (int*)(wsf + OFF_IDX);
    int* flagsb = (int*)(wsf + OFF_FLAGS);
    int* dflag  = (int*)(wsf + OFF_DFLAG);

    detect_kernel<<<1, 64, 0, stream>>>((const unsigned short*)d_in[0], dflag);

    const int segoff[9] = {OFF_XF, OFF_EMBW, OFF_EMBB, OFF_W1, OFF_B1,
                           OFF_W2, OFF_B2, OFF_OW, OFF_OB};
    const int segn[9]   = {GN*3, 3*GH, GH, GL*2*GH*GH, GL*GH,
                           GL*GH*GH, GL*GH, GL*GH*3, 3};
    for (int s = 0; s < 9; ++s)
        convert_kernel<<<(segn[s] + 255)/256, 256, 0, stream>>>(
            d_in[s], wsf + segoff[s], segn[s], dflag);

    embed_kernel<<<GN/256, 256, 0, stream>>>(
        wsf + OFF_XF, wsf + OFF_EMBW, wsf + OFF_EMBB, wsf + OFF_H);

    for (int l = 0; l < GL; ++l) {
        const float* hin = wsf + OFF_H + l*GN*HPS;
        float* hout      = wsf + OFF_H + (l+1)*GN*HPS;
        knn2_kernel<<<GN/RPB, NTHR, 0, stream>>>(hin, idxb, flagsb);
        rescue_kernel<<<GN/RPB, 64, 0, stream>>>(hin, flagsb, idxb);
        edgeconv_kernel<<<GN/64, 256, 0, stream>>>(hin, idxb,
            wsf + OFF_W1 + l*2*GH*GH, wsf + OFF_B1 + l*GH,
            wsf + OFF_W2 + l*GH*GH,  wsf + OFF_B2 + l*GH, hout);
    }

    out_kernel<<<GN/256, 256, 0, stream>>>(
        wsf + OFF_H + GN*HPS, wsf + OFF_OW, wsf + OFF_OB, d_out, dflag);
}

// Round 3
// 1356.734 us; speedup vs baseline: 2.2485x; 1.9968x over previous
//
#include <hip/hip_runtime.h>
#include <hip/hip_bf16.h>

#define GN 16384
#define GH 16
#define GK 16
#define GL 4
#define HPS 20            // padded h row: 16 features + sq + 3 pad (80 B, 16B-aligned)

// knn params
#define RPB 32            // rows per block
#define NTHR 1024         // 16 waves; 32 scan-slots (wave x half)
#define CAP 160           // collect buffer capacity per row
#define BSTR 161          // buffer row stride (floats)
#define SSTR 264          // phase-1 sample-merge row stride
#define TILE_C 256        // columns per LDS tile
#define TILE_F (TILE_C*HPS)
#define LDS_TILE (2*RPB*BSTR + 2*RPB)   // tile offset in lds floats
#define LDS_TOT  (LDS_TILE + TILE_F)    // 15488 floats = 60.5 KB

#define INFF __builtin_inff()

// workspace float-offsets
#define OFF_H     0
#define OFF_IDX   (5*GN*HPS)
#define OFF_FLAGS (OFF_IDX + GN*GK)
#define OFF_XF    (OFF_FLAGS + GN)
#define OFF_EMBW  (OFF_XF + GN*3)
#define OFF_EMBB  (OFF_EMBW + 3*GH)
#define OFF_W1    (OFF_EMBB + GH)
#define OFF_B1    (OFF_W1 + GL*2*GH*GH)
#define OFF_B2_   (OFF_B1 + GL*GH)
#define OFF_W2    OFF_B2_
#define OFF_B2    (OFF_W2 + GL*GH*GH)
#define OFF_OW    (OFF_B2 + GL*GH)
#define OFF_OB    (OFF_OW + GL*GH*3)
#define OFF_DFLAG (OFF_OB + 4)

// ---------------------------------------------------------------------------
__global__ void detect_kernel(const unsigned short* __restrict__ raw,
                              int* __restrict__ flag)
{
    if (threadIdx.x == 0 && blockIdx.x == 0) {
        int cnt = 0;
        for (int i = 0; i < 64; ++i) {
            unsigned int bits = ((unsigned int)raw[2*i]) << 16;
            float v = __uint_as_float(bits);
            float a = fabsf(v);
            if (a > 1e-4f && a < 50.f) ++cnt;
        }
        *flag = (cnt >= 32) ? 1 : 0;   // 1 = inputs are bf16
    }
}

__global__ void convert_kernel(const void* __restrict__ src,
                               float* __restrict__ dst, int n,
                               const int* __restrict__ flag)
{
    int i = blockIdx.x * 256 + threadIdx.x;
    if (i >= n) return;
    if (*flag)
        dst[i] = __bfloat162float(((const __hip_bfloat16*)src)[i]);
    else
        dst[i] = ((const float*)src)[i];
}

// ---------------------------------------------------------------------------
__device__ __forceinline__ float distt(const float hi[16], float sqi,
                                       const float* __restrict__ hj)
{
    float4 A = *(const float4*)(hj + 0);
    float4 B = *(const float4*)(hj + 4);
    float4 C = *(const float4*)(hj + 8);
    float4 D = *(const float4*)(hj + 12);
    float sqj = hj[16];
    float d0 = hi[0]*A.x;
    float d1 = hi[1]*A.y;
    d0 = fmaf(hi[2],  A.z, d0);  d1 = fmaf(hi[3],  A.w, d1);
    d0 = fmaf(hi[4],  B.x, d0);  d1 = fmaf(hi[5],  B.y, d1);
    d0 = fmaf(hi[6],  B.z, d0);  d1 = fmaf(hi[7],  B.w, d1);
    d0 = fmaf(hi[8],  C.x, d0);  d1 = fmaf(hi[9],  C.y, d1);
    d0 = fmaf(hi[10], C.z, d0);  d1 = fmaf(hi[11], C.w, d1);
    d0 = fmaf(hi[12], D.x, d0);  d1 = fmaf(hi[13], D.y, d1);
    d0 = fmaf(hi[14], D.z, d0);  d1 = fmaf(hi[15], D.w, d1);
    return fmaf(-2.f, d0 + d1, sqi + sqj);
}

#define LOAD_HI(ptr)                                                        \
    float hi[16]; float sqi;                                                \
    {                                                                       \
        const float* _hr = (ptr);                                           \
        float4 A = *(const float4*)(_hr + 0);                               \
        float4 B = *(const float4*)(_hr + 4);                               \
        float4 C = *(const float4*)(_hr + 8);                               \
        float4 D = *(const float4*)(_hr + 12);                              \
        hi[0]=A.x; hi[1]=A.y; hi[2]=A.z; hi[3]=A.w;                         \
        hi[4]=B.x; hi[5]=B.y; hi[6]=B.z; hi[7]=B.w;                         \
        hi[8]=C.x; hi[9]=C.y; hi[10]=C.z; hi[11]=C.w;                       \
        hi[12]=D.x; hi[13]=D.y; hi[14]=D.z; hi[15]=D.w;                     \
        sqi = _hr[16];                                                      \
    }

// ---------------------------------------------------------------------------
__global__ __launch_bounds__(256) void embed_kernel(
    const float* __restrict__ xf, const float* __restrict__ W,
    const float* __restrict__ b, float* __restrict__ h0)
{
    int i = blockIdx.x * 256 + threadIdx.x;
    float x0 = xf[i*3+0], x1 = xf[i*3+1], x2 = xf[i*3+2];
    float* orow = h0 + i * HPS;
    float sq = 0.f;
#pragma unroll
    for (int c = 0; c < GH; ++c) {
        float t = b[c];
        t = fmaf(x0, W[0*GH+c], t);
        t = fmaf(x1, W[1*GH+c], t);
        t = fmaf(x2, W[2*GH+c], t);
        t = fmaxf(t, 0.f);
        orow[c] = t;
        sq = fmaf(t, t, sq);
    }
    orow[16] = sq;
}

// ---------------------------------------------------------------------------
// Exact kNN: 2-phase threshold-collect, all candidate reads via LDS tiles.
__global__ __launch_bounds__(NTHR, 4) void knn3_kernel(
    const float* __restrict__ hp, int* __restrict__ idxout,
    int* __restrict__ flags)
{
    __shared__ float lds[LDS_TOT];
    float*    bufd = lds;
    int*      bufj = (int*)(lds + RPB*BSTR);
    unsigned* cnt  = (unsigned*)(lds + 2*RPB*BSTR);
    float*    tau  = lds + 2*RPB*BSTR + RPB;
    float*    tile = lds + LDS_TILE;

    const int tid  = threadIdx.x;
    const int r    = tid & 31;          // row-in-block for scan mapping
    const int slot = tid >> 5;          // 0..31 scan slot (wave*2 + half)
    const int row  = blockIdx.x * RPB + r;

    LOAD_HI(hp + row * HPS);

    // cooperative stage of TILE_C columns: j = tb + (c << sh)
#define STAGE(tb, sh)                                                        \
    for (int v = tid; v < TILE_C*5; v += NTHR) {                             \
        int c = v / 5;                                                       \
        int f = v - c*5;                                                     \
        ((float4*)tile)[v] = ((const float4*)hp)[((tb) + (c << (sh)))*5 + f];\
    }

    // ---- phase 1: sample every 4th column; per-lane top-8 values
    float t8[8];
#pragma unroll
    for (int s = 0; s < 8; ++s) t8[s] = INFF;
    float mx = INFF; int mxs = 0;
    for (int k = 0; k < GN/1024; ++k) {         // 16 sample tiles
        __syncthreads();
        STAGE(k*1024, 2);
        __syncthreads();
        const float* sb = tile + (slot*8)*HPS;
#pragma unroll 2
        for (int t = 0; t < 8; ++t) {
            int j = k*1024 + ((slot*8 + t) << 2);
            float d = distt(hi, sqi, sb + t*HPS);
            if (j == row) d = INFF;
            if (d < mx) {
#pragma unroll
                for (int q = 0; q < 8; ++q) { bool cs = (q == mxs); t8[q] = cs ? d : t8[q]; }
                mx = t8[0]; mxs = 0;
#pragma unroll
                for (int q = 1; q < 8; ++q) { bool cs = (t8[q] >= mx); mx = cs ? t8[q] : mx; mxs = cs ? q : mxs; }
            }
        }
    }
    __syncthreads();   // tile reads done; now overlay sample-merge region
    *(float4*)(lds + r*SSTR + slot*8)     = make_float4(t8[0], t8[1], t8[2], t8[3]);
    *(float4*)(lds + r*SSTR + slot*8 + 4) = make_float4(t8[4], t8[5], t8[6], t8[7]);
    __syncthreads();

    // ---- phase 1b: per-row merge (32 lanes/row): tau = 16th smallest sample
    const int mr = tid >> 5, g = tid & 31;
    float s8[8];
    {
        float4 u0 = *(const float4*)(lds + mr*SSTR + g*8);
        float4 u1 = *(const float4*)(lds + mr*SSTR + g*8 + 4);
        s8[0]=u0.x; s8[1]=u0.y; s8[2]=u0.z; s8[3]=u0.w;
        s8[4]=u1.x; s8[5]=u1.y; s8[6]=u1.z; s8[7]=u1.w;
    }
    float tval = INFF;
#pragma unroll
    for (int k = 0; k < 16; ++k) {
        float md = s8[0]; int ms = 0;
#pragma unroll
        for (int q = 1; q < 8; ++q) { bool cs = (s8[q] < md); md = cs ? s8[q] : md; ms = cs ? q : ms; }
        float rv = md; int rl = g;
#pragma unroll
        for (int m = 1; m <= 16; m <<= 1) {
            float ov = __shfl_xor(rv, m, 32);
            int   ol = __shfl_xor(rl, m, 32);
            bool cs = (ov < rv) || (ov == rv && ol < rl);
            rv = cs ? ov : rv; rl = cs ? ol : rl;
        }
        if (rl == g) {
#pragma unroll
            for (int q = 0; q < 8; ++q) if (q == ms) s8[q] = INFF;
        }
        tval = rv;
    }
    if (g == 0) tau[mr] = tval;
    if (tid < RPB) cnt[tid] = 0;
    __syncthreads();

    // ---- phase 2: full scan via tiles, append d <= tau.
    // count >= 16 guaranteed: sampled bits re-read identically from LDS.
    const float taur = tau[r];
    const int rowoff = r * BSTR;
    for (int k = 0; k < GN/TILE_C; ++k) {       // 64 tiles
        __syncthreads();
        STAGE(k*TILE_C, 0);
        __syncthreads();
        const float* sb = tile + (slot*8)*HPS;
#pragma unroll 2
        for (int t = 0; t < 8; ++t) {
            int j = k*TILE_C + slot*8 + t;
            float d = distt(hi, sqi, sb + t*HPS);
            if (j == row) d = INFF;
            if (d <= taur) {
                unsigned pos = atomicAdd(&cnt[r], 1u);
                if (pos < CAP) { bufd[rowoff + pos] = d; bufj[rowoff + pos] = j; }
            }
        }
    }
    __syncthreads();

    // ---- phase 3: exact top-16 of buffer per row (32 lanes/row), (d,j) order
    const unsigned c   = cnt[mr];
    const unsigned lim = c < CAP ? c : CAP;
    float sd[5]; int sj[5];
#pragma unroll
    for (int e = 0; e < 5; ++e) {
        unsigned p = (unsigned)g + 32u*e;
        bool v = p < lim;
        sd[e] = v ? bufd[mr*BSTR + p] : INFF;
        sj[e] = v ? bufj[mr*BSTR + p] : 0x7fffffff;
    }
    const int rowg = blockIdx.x * RPB + mr;
#pragma unroll
    for (int k = 0; k < GK; ++k) {
        float md = sd[0]; int mj = sj[0]; int ms = 0;
#pragma unroll
        for (int e = 1; e < 5; ++e) {
            bool cs = (sd[e] < md) || (sd[e] == md && sj[e] < mj);
            md = cs ? sd[e] : md; mj = cs ? sj[e] : mj; ms = cs ? e : ms;
        }
        float rd = md; int rj = mj;
#pragma unroll
        for (int m = 1; m <= 16; m <<= 1) {
            float od = __shfl_xor(rd, m, 32);
            int   oj = __shfl_xor(rj, m, 32);
            bool cs = (od < rd) || (od == rd && oj < rj);
            rd = cs ? od : rd; rj = cs ? oj : rj;
        }
        if (g == 0) idxout[rowg*GK + k] = rj;
        if (rd == md && rj == mj) {
#pragma unroll
            for (int e = 0; e < 5; ++e) if (e == ms) { sd[e] = INFF; sj[e] = 0x7fffffff; }
        }
    }
    if (g == 0) flags[rowg] = (c > CAP || c < 16u) ? 1 : 0;
#undef STAGE
}

// ---------------------------------------------------------------------------
// Exact full-scan fallback for rows whose buffer overflowed (P ~ 1e-6/row).
__global__ __launch_bounds__(64) void rescue_kernel(
    const float* __restrict__ hp, const int* __restrict__ flags,
    int* __restrict__ idxout)
{
    const int lane = threadIdx.x;
    const int r0 = blockIdx.x * RPB;
    int f = (lane < RPB) ? flags[r0 + lane] : 0;
    if (__ballot(f != 0) == 0ull) return;
    for (int rr = 0; rr < RPB; ++rr) {
        if (flags[r0 + rr] == 0) continue;
        const int row = r0 + rr;
        LOAD_HI(hp + row * HPS);
        float topd[GK]; int topi[GK];
#pragma unroll
        for (int s = 0; s < GK; ++s) { topd[s] = INFF; topi[s] = -1; }
        float mx = INFF; int mxs = 0;
        for (int s = 0; s < GN/64; ++s) {
            int j = lane + (s << 6);
            float d = distt(hi, sqi, hp + j * HPS);
            if (j == row) d = INFF;
            if (d < mx) {
#pragma unroll
                for (int q = 0; q < GK; ++q) { bool cs = (q == mxs); topd[q] = cs ? d : topd[q]; topi[q] = cs ? j : topi[q]; }
                mx = topd[0]; mxs = 0;
#pragma unroll
                for (int q = 1; q < GK; ++q) { bool cs = (topd[q] >= mx); mx = cs ? topd[q] : mx; mxs = cs ? q : mxs; }
            }
        }
#pragma unroll
        for (int t = 0; t < GK; ++t) {
            float md = topd[0]; int mj = topi[0]; int ms = 0;
#pragma unroll
            for (int q = 1; q < GK; ++q) {
                bool cs = (topd[q] < md) || (topd[q] == md && topi[q] < mj);
                md = cs ? topd[q] : md; mj = cs ? topi[q] : mj; ms = cs ? q : ms;
            }
            float rd = md; int rj = mj;
#pragma unroll
            for (int m = 1; m <= 32; m <<= 1) {
                float od = __shfl_xor(rd, m, 64);
                int   oj = __shfl_xor(rj, m, 64);
                bool cs = (od < rd) || (od == rd && oj < rj);
                rd = cs ? od : rd; rj = cs ? oj : rj;
            }
            if (lane == 0) idxout[row*GK + t] = rj;
            if (rd == md && rj == mj) {
#pragma unroll
                for (int q = 0; q < GK; ++q) if (q == ms) { topd[q] = INFF; topi[q] = 0x7fffffff; }
            }
        }
    }
}

// ---------------------------------------------------------------------------
__global__ __launch_bounds__(256) void edgeconv_kernel(
    const float* __restrict__ hin, const int* __restrict__ idx,
    const float* __restrict__ W1, const float* __restrict__ b1,
    const float* __restrict__ W2, const float* __restrict__ b2,
    float* __restrict__ hout)
{
    __shared__ float sW1[2*GH*GH], sW2[GH*GH], sb1[GH], sb2[GH];
    const int tid = threadIdx.x;
    for (int t = tid; t < 2*GH*GH; t += 256) sW1[t] = W1[t];
    for (int t = tid; t < GH*GH;  t += 256) sW2[t] = W2[t];
    if (tid < GH) { sb1[tid] = b1[tid]; sb2[tid] = b2[tid]; }
    __syncthreads();

    const int t4 = tid & 3;
    const int i = blockIdx.x * 64 + (tid >> 2);

    LOAD_HI(hin + i * HPS);
    (void)sqi;
    float ci[GH];
#pragma unroll
    for (int c = 0; c < GH; ++c) {
        float s = sb1[c];
#pragma unroll
        for (int d = 0; d < GH; ++d) s = fmaf(hi[d], sW1[d*GH+c], s);
        ci[c] = s;
    }
    float acc[GH];
#pragma unroll
    for (int c = 0; c < GH; ++c) acc[c] = 0.f;

    const int4 jj = *(const int4*)(idx + i*GK + t4*4);
    const int js[4] = { jj.x, jj.y, jj.z, jj.w };
#pragma unroll
    for (int nn = 0; nn < 4; ++nn) {
        const int j = js[nn];
        float dj[GH];
        {
            const float* hv = hin + j * HPS;
            float4 A = *(const float4*)(hv + 0);
            float4 B = *(const float4*)(hv + 4);
            float4 C = *(const float4*)(hv + 8);
            float4 D = *(const float4*)(hv + 12);
            dj[0]=A.x-hi[0]; dj[1]=A.y-hi[1]; dj[2]=A.z-hi[2]; dj[3]=A.w-hi[3];
            dj[4]=B.x-hi[4]; dj[5]=B.y-hi[5]; dj[6]=B.z-hi[6]; dj[7]=B.w-hi[7];
            dj[8]=C.x-hi[8]; dj[9]=C.y-hi[9]; dj[10]=C.z-hi[10]; dj[11]=C.w-hi[11];
            dj[12]=D.x-hi[12]; dj[13]=D.y-hi[13]; dj[14]=D.z-hi[14]; dj[15]=D.w-hi[15];
        }
        float msg[GH];
#pragma unroll
        for (int c = 0; c < GH; ++c) {
            float s = ci[c];
#pragma unroll
            for (int d = 0; d < GH; ++d) s = fmaf(dj[d], sW1[(GH+d)*GH+c], s);
            msg[c] = fmaxf(s, 0.f);
        }
#pragma unroll
        for (int c2 = 0; c2 < GH; ++c2) {
            float s = acc[c2];
#pragma unroll
            for (int c = 0; c < GH; ++c) s = fmaf(msg[c], sW2[c*GH+c2], s);
            acc[c2] = s;
        }
    }
#pragma unroll
    for (int c = 0; c < GH; ++c) {
        acc[c] += __shfl_xor(acc[c], 1);
        acc[c] += __shfl_xor(acc[c], 2);
    }
    if (t4 == 0) {
        float* orow = hout + i * HPS;
        float sq = 0.f;
#pragma unroll
        for (int c = 0; c < GH; ++c) {
            float v = acc[c] * (1.f/16.f) + sb2[c];
            orow[c] = v;
            sq = fmaf(v, v, sq);
        }
        orow[16] = sq;
    }
}

// ---------------------------------------------------------------------------
__global__ __launch_bounds__(256) void out_kernel(
    const float* __restrict__ hbase, const float* __restrict__ W,
    const float* __restrict__ b, void* __restrict__ out,
    const int* __restrict__ flag)
{
    int i = blockIdx.x * 256 + threadIdx.x;
    float a0 = b[0], a1 = b[1], a2 = b[2];
#pragma unroll
    for (int l = 0; l < GL; ++l) {
        const float* hp = hbase + l * GN * HPS + i * HPS;
#pragma unroll
        for (int c = 0; c < GH; ++c) {
            const float v = hp[c];
            const float* wr = W + (l * GH + c) * 3;
            a0 = fmaf(v, wr[0], a0);
            a1 = fmaf(v, wr[1], a1);
            a2 = fmaf(v, wr[2], a2);
        }
    }
    if (*flag) {
        __hip_bfloat16* o = (__hip_bfloat16*)out;
        o[i*3+0] = __float2bfloat16(a0);
        o[i*3+1] = __float2bfloat16(a1);
        o[i*3+2] = __float2bfloat16(a2);
    } else {
        float* o = (float*)out;
        o[i*3+0] = a0; o[i*3+1] = a1; o[i*3+2] = a2;
    }
}

// ---------------------------------------------------------------------------
extern "C" void kernel_launch(void* const* d_in, const int* in_sizes, int n_in,
                              void* d_out, int out_size, void* d_ws, size_t ws_size,
                              hipStream_t stream)
{
    float* wsf  = (float*)d_ws;
    int* idxb   = (int*)(wsf + OFF_IDX);
    int* flagsb = (int*)(wsf + OFF_FLAGS);
    int* dflag  = (int*)(wsf + OFF_DFLAG);

    detect_kernel<<<1, 64, 0, stream>>>((const unsigned short*)d_in[0], dflag);

    const int segoff[9] = {OFF_XF, OFF_EMBW, OFF_EMBB, OFF_W1, OFF_B1,
                           OFF_W2, OFF_B2, OFF_OW, OFF_OB};
    const int segn[9]   = {GN*3, 3*GH, GH, GL*2*GH*GH, GL*GH,
                           GL*GH*GH, GL*GH, GL*GH*3, 3};
    for (int s = 0; s < 9; ++s)
        convert_kernel<<<(segn[s] + 255)/256, 256, 0, stream>>>(
            d_in[s], wsf + segoff[s], segn[s], dflag);

    embed_kernel<<<GN/256, 256, 0, stream>>>(
        wsf + OFF_XF, wsf + OFF_EMBW, wsf + OFF_EMBB, wsf + OFF_H);

    for (int l = 0; l < GL; ++l) {
        const float* hin = wsf + OFF_H + l*GN*HPS;
        float* hout      = wsf + OFF_H + (l+1)*GN*HPS;
        knn3_kernel<<<GN/RPB, NTHR, 0, stream>>>(hin, idxb, flagsb);
        rescue_kernel<<<GN/RPB, 64, 0, stream>>>(hin, flagsb, idxb);
        edgeconv_kernel<<<GN/64, 256, 0, stream>>>(hin, idxb,
            wsf + OFF_W1 + l*2*GH*GH, wsf + OFF_B1 + l*GH,
            wsf + OFF_W2 + l*GH*GH,  wsf + OFF_B2 + l*GH, hout);
    }

    out_kernel<<<GN/256, 256, 0, stream>>>(
        wsf + OFF_H + GN*HPS, wsf + OFF_OW, wsf + OFF_OB, d_out, dflag);
}

// Round 4
// 1270.669 us; speedup vs baseline: 2.4008x; 1.0677x over previous
//
#include <hip/hip_runtime.h>
#include <hip/hip_bf16.h>

#define GN 16384
#define GH 16
#define GK 16
#define GL 4
#define HPS 20            // padded h row: 16 features + sq + 3 pad (80 B, 16B-aligned)

// knn params
#define RPB 32            // rows per block
#define NTHR 1024         // 16 waves; 8 row-quads x 128 col-slots
#define CAP 160           // collect buffer capacity per row
#define BSTR 161          // buffer row stride (floats)
#define SSTR 264          // phase-1 sample-merge row stride
#define TILE_C 256        // columns per LDS tile
#define TILE_F (TILE_C*HPS)
#define LDS_TILE (2*RPB*BSTR + 2*RPB)   // tile offset in lds floats
#define LDS_TOT  (LDS_TILE + TILE_F)    // 15488 floats = 60.5 KB

#define INFF __builtin_inff()

// workspace float-offsets
#define OFF_H     0
#define OFF_IDX   (5*GN*HPS)
#define OFF_FLAGS (OFF_IDX + GN*GK)
#define OFF_XF    (OFF_FLAGS + GN)
#define OFF_EMBW  (OFF_XF + GN*3)
#define OFF_EMBB  (OFF_EMBW + 3*GH)
#define OFF_W1    (OFF_EMBB + GH)
#define OFF_B1    (OFF_W1 + GL*2*GH*GH)
#define OFF_W2    (OFF_B1 + GL*GH)
#define OFF_B2    (OFF_W2 + GL*GH*GH)
#define OFF_OW    (OFF_B2 + GL*GH)
#define OFF_OB    (OFF_OW + GL*GH*3)
#define OFF_DFLAG (OFF_OB + 4)

// ---------------------------------------------------------------------------
__global__ void detect_kernel(const unsigned short* __restrict__ raw,
                              int* __restrict__ flag)
{
    if (threadIdx.x == 0 && blockIdx.x == 0) {
        int cnt = 0;
        for (int i = 0; i < 64; ++i) {
            unsigned int bits = ((unsigned int)raw[2*i]) << 16;
            float v = __uint_as_float(bits);
            float a = fabsf(v);
            if (a > 1e-4f && a < 50.f) ++cnt;
        }
        *flag = (cnt >= 32) ? 1 : 0;   // 1 = inputs are bf16
    }
}

__global__ void convert_kernel(const void* __restrict__ src,
                               float* __restrict__ dst, int n,
                               const int* __restrict__ flag)
{
    int i = blockIdx.x * 256 + threadIdx.x;
    if (i >= n) return;
    if (*flag)
        dst[i] = __bfloat162float(((const __hip_bfloat16*)src)[i]);
    else
        dst[i] = ((const float*)src)[i];
}

// ---------------------------------------------------------------------------
__device__ __forceinline__ float distt(const float hi[16], float sqi,
                                       const float* __restrict__ hj)
{
    float4 A = *(const float4*)(hj + 0);
    float4 B = *(const float4*)(hj + 4);
    float4 C = *(const float4*)(hj + 8);
    float4 D = *(const float4*)(hj + 12);
    float sqj = hj[16];
    float d0 = hi[0]*A.x;
    float d1 = hi[1]*A.y;
    d0 = fmaf(hi[2],  A.z, d0);  d1 = fmaf(hi[3],  A.w, d1);
    d0 = fmaf(hi[4],  B.x, d0);  d1 = fmaf(hi[5],  B.y, d1);
    d0 = fmaf(hi[6],  B.z, d0);  d1 = fmaf(hi[7],  B.w, d1);
    d0 = fmaf(hi[8],  C.x, d0);  d1 = fmaf(hi[9],  C.y, d1);
    d0 = fmaf(hi[10], C.z, d0);  d1 = fmaf(hi[11], C.w, d1);
    d0 = fmaf(hi[12], D.x, d0);  d1 = fmaf(hi[13], D.y, d1);
    d0 = fmaf(hi[14], D.z, d0);  d1 = fmaf(hi[15], D.w, d1);
    return fmaf(-2.f, d0 + d1, sqi + sqj);
}

#define LOAD_HI(ptr)                                                        \
    float hi[16]; float sqi;                                                \
    {                                                                       \
        const float* _hr = (ptr);                                           \
        float4 A = *(const float4*)(_hr + 0);                               \
        float4 B = *(const float4*)(_hr + 4);                               \
        float4 C = *(const float4*)(_hr + 8);                               \
        float4 D = *(const float4*)(_hr + 12);                              \
        hi[0]=A.x; hi[1]=A.y; hi[2]=A.z; hi[3]=A.w;                         \
        hi[4]=B.x; hi[5]=B.y; hi[6]=B.z; hi[7]=B.w;                         \
        hi[8]=C.x; hi[9]=C.y; hi[10]=C.z; hi[11]=C.w;                       \
        hi[12]=D.x; hi[13]=D.y; hi[14]=D.z; hi[15]=D.w;                     \
        sqi = _hr[16];                                                      \
    }

// ---------------------------------------------------------------------------
__global__ __launch_bounds__(256) void embed_kernel(
    const float* __restrict__ xf, const float* __restrict__ W,
    const float* __restrict__ b, float* __restrict__ h0)
{
    int i = blockIdx.x * 256 + threadIdx.x;
    float x0 = xf[i*3+0], x1 = xf[i*3+1], x2 = xf[i*3+2];
    float* orow = h0 + i * HPS;
    float sq = 0.f;
#pragma unroll
    for (int c = 0; c < GH; ++c) {
        float t = b[c];
        t = fmaf(x0, W[0*GH+c], t);
        t = fmaf(x1, W[1*GH+c], t);
        t = fmaf(x2, W[2*GH+c], t);
        t = fmaxf(t, 0.f);
        orow[c] = t;
        sq = fmaf(t, t, sq);
    }
    orow[16] = sq;
}

// ---------------------------------------------------------------------------
// Exact kNN: 2-phase threshold-collect; LDS tiles; 4-row register blocking.
__global__ __launch_bounds__(NTHR, 4) void knn4_kernel(
    const float* __restrict__ hp, int* __restrict__ idxout,
    int* __restrict__ flags)
{
    __shared__ float lds[LDS_TOT];
    float*    bufd = lds;
    int*      bufj = (int*)(lds + RPB*BSTR);
    unsigned* cnt  = (unsigned*)(lds + 2*RPB*BSTR);
    float*    tau  = lds + 2*RPB*BSTR + RPB;
    float*    tile = lds + LDS_TILE;
    float4*   tile4 = (float4*)tile;

    const int tid = threadIdx.x;
    const int q   = tid & 7;            // row-quad 0..7 (rows q*4..q*4+3)
    const int s   = tid >> 3;           // col-slot 0..127
    const int r0  = blockIdx.x * RPB + q * 4;   // first global row of quad

    // ---- load 4 center rows into registers
    float hi[4][16]; float sqi[4];
#pragma unroll
    for (int rr = 0; rr < 4; ++rr) {
        const float* hr = hp + (r0 + rr) * HPS;
        float4 A = *(const float4*)(hr + 0);
        float4 B = *(const float4*)(hr + 4);
        float4 C = *(const float4*)(hr + 8);
        float4 D = *(const float4*)(hr + 12);
        hi[rr][0]=A.x; hi[rr][1]=A.y; hi[rr][2]=A.z; hi[rr][3]=A.w;
        hi[rr][4]=B.x; hi[rr][5]=B.y; hi[rr][6]=B.z; hi[rr][7]=B.w;
        hi[rr][8]=C.x; hi[rr][9]=C.y; hi[rr][10]=C.z; hi[rr][11]=C.w;
        hi[rr][12]=D.x; hi[rr][13]=D.y; hi[rr][14]=D.z; hi[rr][15]=D.w;
        sqi[rr] = hr[16];
    }

    // ---- staging constants (float4 units); tile = 256 cols x 5 float4
    const int c0 = tid / 5, f0 = tid - 5*c0;
    const bool has2 = tid < (TILE_C*5 - NTHR);          // 256 threads
    const int v1 = tid + NTHR;
    const int c1 = v1 / 5, f1 = v1 - 5*c1;
    const float4* hp4 = (const float4*)hp;
    const int o1a = 20*c0 + f0, o1b = 20*c1 + f1;       // phase-1 (stride-4 cols)
    const int o2a = 5*c0 + f0,  o2b = 5*c1 + f1;        // phase-2 (contiguous)

    // distance for 4 rows vs staged col; sets dd[0..3]
#define DIST4(hjp, jglob, dd)                                               \
    {                                                                       \
        const float* _hj = (hjp);                                           \
        float4 A = *(const float4*)(_hj + 0);                               \
        float4 B = *(const float4*)(_hj + 4);                               \
        float4 C = *(const float4*)(_hj + 8);                               \
        float4 D = *(const float4*)(_hj + 12);                              \
        float sqj = _hj[16];                                                \
        _Pragma("unroll")                                                   \
        for (int rr = 0; rr < 4; ++rr) {                                    \
            float d0 = hi[rr][0]*A.x;                                       \
            float d1 = hi[rr][1]*A.y;                                       \
            d0 = fmaf(hi[rr][2],  A.z, d0);  d1 = fmaf(hi[rr][3],  A.w, d1);\
            d0 = fmaf(hi[rr][4],  B.x, d0);  d1 = fmaf(hi[rr][5],  B.y, d1);\
            d0 = fmaf(hi[rr][6],  B.z, d0);  d1 = fmaf(hi[rr][7],  B.w, d1);\
            d0 = fmaf(hi[rr][8],  C.x, d0);  d1 = fmaf(hi[rr][9],  C.y, d1);\
            d0 = fmaf(hi[rr][10], C.z, d0);  d1 = fmaf(hi[rr][11], C.w, d1);\
            d0 = fmaf(hi[rr][12], D.x, d0);  d1 = fmaf(hi[rr][13], D.y, d1);\
            d0 = fmaf(hi[rr][14], D.z, d0);  d1 = fmaf(hi[rr][15], D.w, d1);\
            dd[rr] = fmaf(-2.f, d0 + d1, sqi[rr] + sqj);                    \
        }                                                                   \
        unsigned u = (unsigned)((jglob) - r0);                              \
        if (u < 4u) {                                                       \
            _Pragma("unroll")                                               \
            for (int rr = 0; rr < 4; ++rr)                                  \
                if (u == (unsigned)rr) dd[rr] = INFF;                       \
        }                                                                   \
    }

    // ---- phase 1: sample every 4th column; branchless per-row top-2 stream
    float m1[4], m2[4];
#pragma unroll
    for (int rr = 0; rr < 4; ++rr) { m1[rr] = INFF; m2[rr] = INFF; }
    {
        float4 ga, gb;
        ga = hp4[o1a];
        if (has2) gb = hp4[o1b];
        for (int k = 0; k < 16; ++k) {
            __syncthreads();
            tile4[tid] = ga;
            if (has2) tile4[v1] = gb;
            if (k + 1 < 16) {
                ga = hp4[5120*(k+1) + o1a];
                if (has2) gb = hp4[5120*(k+1) + o1b];
            }
            __syncthreads();
#pragma unroll
            for (int cc = 0; cc < 2; ++cc) {
                const int lc = s + cc*128;
                const int j = 4*(256*k + lc);
                float dd[4];
                DIST4(tile + lc*HPS, j, dd);
#pragma unroll
                for (int rr = 0; rr < 4; ++rr) {
                    float t = fmaxf(m1[rr], dd[rr]);
                    m1[rr] = fminf(m1[rr], dd[rr]);
                    m2[rr] = fminf(m2[rr], t);
                }
            }
        }
    }
    // stash per-(thread,row) top-2 into buffer region for the row merge
#pragma unroll
    for (int rr = 0; rr < 4; ++rr) {
        lds[(q*4+rr)*SSTR + s*2 + 0] = m1[rr];
        lds[(q*4+rr)*SSTR + s*2 + 1] = m2[rr];
    }
    __syncthreads();

    // ---- phase 1b: per-row merge (32 lanes/row): tau = 16th smallest sample
    const int mr = tid >> 5, g = tid & 31;
    float s8[8];
    {
        float4 u0 = *(const float4*)(lds + mr*SSTR + g*8);
        float4 u1 = *(const float4*)(lds + mr*SSTR + g*8 + 4);
        s8[0]=u0.x; s8[1]=u0.y; s8[2]=u0.z; s8[3]=u0.w;
        s8[4]=u1.x; s8[5]=u1.y; s8[6]=u1.z; s8[7]=u1.w;
    }
    float tval = INFF;
#pragma unroll
    for (int k = 0; k < 16; ++k) {
        float md = s8[0]; int ms = 0;
#pragma unroll
        for (int e = 1; e < 8; ++e) { bool cs = (s8[e] < md); md = cs ? s8[e] : md; ms = cs ? e : ms; }
        float rv = md; int rl = g;
#pragma unroll
        for (int m = 1; m <= 16; m <<= 1) {
            float ov = __shfl_xor(rv, m, 32);
            int   ol = __shfl_xor(rl, m, 32);
            bool cs = (ov < rv) || (ov == rv && ol < rl);
            rv = cs ? ov : rv; rl = cs ? ol : rl;
        }
        if (rl == g) {
#pragma unroll
            for (int e = 0; e < 8; ++e) if (e == ms) s8[e] = INFF;
        }
        tval = rv;
    }
    if (g == 0) tau[mr] = tval;
    if (tid < RPB) cnt[tid] = 0;
    __syncthreads();

    // ---- phase 2: full scan via tiles, append d <= tau (identical arithmetic
    // to phase 1 -> count >= 16 guaranteed).
    float tau4[4];
#pragma unroll
    for (int rr = 0; rr < 4; ++rr) tau4[rr] = tau[q*4+rr];
    {
        float4 ga, gb;
        ga = hp4[o2a];
        if (has2) gb = hp4[o2b];
        for (int k = 0; k < GN/TILE_C; ++k) {      // 64 tiles
            __syncthreads();
            tile4[tid] = ga;
            if (has2) tile4[v1] = gb;
            if (k + 1 < GN/TILE_C) {
                ga = hp4[1280*(k+1) + o2a];
                if (has2) gb = hp4[1280*(k+1) + o2b];
            }
            __syncthreads();
#pragma unroll
            for (int cc = 0; cc < 2; ++cc) {
                const int lc = s + cc*128;
                const int j = 256*k + lc;
                float dd[4];
                DIST4(tile + lc*HPS, j, dd);
                bool p0 = dd[0] <= tau4[0], p1 = dd[1] <= tau4[1];
                bool p2 = dd[2] <= tau4[2], p3 = dd[3] <= tau4[3];
                if (p0 | p1 | p2 | p3) {
#pragma unroll
                    for (int rr = 0; rr < 4; ++rr) {
                        if (dd[rr] <= tau4[rr]) {
                            unsigned pos = atomicAdd(&cnt[q*4+rr], 1u);
                            if (pos < CAP) {
                                bufd[(q*4+rr)*BSTR + pos] = dd[rr];
                                bufj[(q*4+rr)*BSTR + pos] = j;
                            }
                        }
                    }
                }
            }
        }
    }
    __syncthreads();

    // ---- phase 3: exact top-16 of buffer per row (32 lanes/row), (d,j) order
    const unsigned c   = cnt[mr];
    const unsigned lim = c < CAP ? c : CAP;
    float sd[5]; int sj[5];
#pragma unroll
    for (int e = 0; e < 5; ++e) {
        unsigned p = (unsigned)g + 32u*e;
        bool v = p < lim;
        sd[e] = v ? bufd[mr*BSTR + p] : INFF;
        sj[e] = v ? bufj[mr*BSTR + p] : 0x7fffffff;
    }
    const int rowg = blockIdx.x * RPB + mr;
#pragma unroll
    for (int k = 0; k < GK; ++k) {
        float md = sd[0]; int mj = sj[0]; int ms = 0;
#pragma unroll
        for (int e = 1; e < 5; ++e) {
            bool cs = (sd[e] < md) || (sd[e] == md && sj[e] < mj);
            md = cs ? sd[e] : md; mj = cs ? sj[e] : mj; ms = cs ? e : ms;
        }
        float rd = md; int rj = mj;
#pragma unroll
        for (int m = 1; m <= 16; m <<= 1) {
            float od = __shfl_xor(rd, m, 32);
            int   oj = __shfl_xor(rj, m, 32);
            bool cs = (od < rd) || (od == rd && oj < rj);
            rd = cs ? od : rd; rj = cs ? oj : rj;
        }
        if (g == 0) idxout[rowg*GK + k] = rj;
        if (rd == md && rj == mj) {
#pragma unroll
            for (int e = 0; e < 5; ++e) if (e == ms) { sd[e] = INFF; sj[e] = 0x7fffffff; }
        }
    }
    if (g == 0) flags[rowg] = (c > CAP || c < 16u) ? 1 : 0;
#undef DIST4
}

// ---------------------------------------------------------------------------
// Exact full-scan fallback for rows whose buffer overflowed (P ~ 1e-6/row).
__global__ __launch_bounds__(64) void rescue_kernel(
    const float* __restrict__ hp, const int* __restrict__ flags,
    int* __restrict__ idxout)
{
    const int lane = threadIdx.x;
    const int r0 = blockIdx.x * RPB;
    int f = (lane < RPB) ? flags[r0 + lane] : 0;
    if (__ballot(f != 0) == 0ull) return;
    for (int rr = 0; rr < RPB; ++rr) {
        if (flags[r0 + rr] == 0) continue;
        const int row = r0 + rr;
        LOAD_HI(hp + row * HPS);
        float topd[GK]; int topi[GK];
#pragma unroll
        for (int s = 0; s < GK; ++s) { topd[s] = INFF; topi[s] = -1; }
        float mx = INFF; int mxs = 0;
        for (int s = 0; s < GN/64; ++s) {
            int j = lane + (s << 6);
            float d = distt(hi, sqi, hp + j * HPS);
            if (j == row) d = INFF;
            if (d < mx) {
#pragma unroll
                for (int e = 0; e < GK; ++e) { bool cs = (e == mxs); topd[e] = cs ? d : topd[e]; topi[e] = cs ? j : topi[e]; }
                mx = topd[0]; mxs = 0;
#pragma unroll
                for (int e = 1; e < GK; ++e) { bool cs = (topd[e] >= mx); mx = cs ? topd[e] : mx; mxs = cs ? e : mxs; }
            }
        }
#pragma unroll
        for (int t = 0; t < GK; ++t) {
            float md = topd[0]; int mj = topi[0]; int ms = 0;
#pragma unroll
            for (int e = 1; e < GK; ++e) {
                bool cs = (topd[e] < md) || (topd[e] == md && topi[e] < mj);
                md = cs ? topd[e] : md; mj = cs ? topi[e] : mj; ms = cs ? e : ms;
            }
            float rd = md; int rj = mj;
#pragma unroll
            for (int m = 1; m <= 32; m <<= 1) {
                float od = __shfl_xor(rd, m, 64);
                int   oj = __shfl_xor(rj, m, 64);
                bool cs = (od < rd) || (od == rd && oj < rj);
                rd = cs ? od : rd; rj = cs ? oj : rj;
            }
            if (lane == 0) idxout[row*GK + t] = rj;
            if (rd == md && rj == mj) {
#pragma unroll
                for (int e = 0; e < GK; ++e) if (e == ms) { topd[e] = INFF; topi[e] = 0x7fffffff; }
            }
        }
    }
}

// ---------------------------------------------------------------------------
__global__ __launch_bounds__(256) void edgeconv_kernel(
    const float* __restrict__ hin, const int* __restrict__ idx,
    const float* __restrict__ W1, const float* __restrict__ b1,
    const float* __restrict__ W2, const float* __restrict__ b2,
    float* __restrict__ hout)
{
    __shared__ float sW1[2*GH*GH], sW2[GH*GH], sb1[GH], sb2[GH];
    const int tid = threadIdx.x;
    for (int t = tid; t < 2*GH*GH; t += 256) sW1[t] = W1[t];
    for (int t = tid; t < GH*GH;  t += 256) sW2[t] = W2[t];
    if (tid < GH) { sb1[tid] = b1[tid]; sb2[tid] = b2[tid]; }
    __syncthreads();

    const int t4 = tid & 3;
    const int i = blockIdx.x * 64 + (tid >> 2);

    LOAD_HI(hin + i * HPS);
    (void)sqi;
    float ci[GH];
#pragma unroll
    for (int c = 0; c < GH; ++c) {
        float s = sb1[c];
#pragma unroll
        for (int d = 0; d < GH; ++d) s = fmaf(hi[d], sW1[d*GH+c], s);
        ci[c] = s;
    }
    float acc[GH];
#pragma unroll
    for (int c = 0; c < GH; ++c) acc[c] = 0.f;

    const int4 jj = *(const int4*)(idx + i*GK + t4*4);
    const int js[4] = { jj.x, jj.y, jj.z, jj.w };
#pragma unroll
    for (int nn = 0; nn < 4; ++nn) {
        const int j = js[nn];
        float dj[GH];
        {
            const float* hv = hin + j * HPS;
            float4 A = *(const float4*)(hv + 0);
            float4 B = *(const float4*)(hv + 4);
            float4 C = *(const float4*)(hv + 8);
            float4 D = *(const float4*)(hv + 12);
            dj[0]=A.x-hi[0]; dj[1]=A.y-hi[1]; dj[2]=A.z-hi[2]; dj[3]=A.w-hi[3];
            dj[4]=B.x-hi[4]; dj[5]=B.y-hi[5]; dj[6]=B.z-hi[6]; dj[7]=B.w-hi[7];
            dj[8]=C.x-hi[8]; dj[9]=C.y-hi[9]; dj[10]=C.z-hi[10]; dj[11]=C.w-hi[11];
            dj[12]=D.x-hi[12]; dj[13]=D.y-hi[13]; dj[14]=D.z-hi[14]; dj[15]=D.w-hi[15];
        }
        float msg[GH];
#pragma unroll
        for (int c = 0; c < GH; ++c) {
            float s = ci[c];
#pragma unroll
            for (int d = 0; d < GH; ++d) s = fmaf(dj[d], sW1[(GH+d)*GH+c], s);
            msg[c] = fmaxf(s, 0.f);
        }
#pragma unroll
        for (int c2 = 0; c2 < GH; ++c2) {
            float s = acc[c2];
#pragma unroll
            for (int c = 0; c < GH; ++c) s = fmaf(msg[c], sW2[c*GH+c2], s);
            acc[c2] = s;
        }
    }
#pragma unroll
    for (int c = 0; c < GH; ++c) {
        acc[c] += __shfl_xor(acc[c], 1);
        acc[c] += __shfl_xor(acc[c], 2);
    }
    if (t4 == 0) {
        float* orow = hout + i * HPS;
        float sq = 0.f;
#pragma unroll
        for (int c = 0; c < GH; ++c) {
            float v = acc[c] * (1.f/16.f) + sb2[c];
            orow[c] = v;
            sq = fmaf(v, v, sq);
        }
        orow[16] = sq;
    }
}

// ---------------------------------------------------------------------------
__global__ __launch_bounds__(256) void out_kernel(
    const float* __restrict__ hbase, const float* __restrict__ W,
    const float* __restrict__ b, void* __restrict__ out,
    const int* __restrict__ flag)
{
    int i = blockIdx.x * 256 + threadIdx.x;
    float a0 = b[0], a1 = b[1], a2 = b[2];
#pragma unroll
    for (int l = 0; l < GL; ++l) {
        const float* hp = hbase + l * GN * HPS + i * HPS;
#pragma unroll
        for (int c = 0; c < GH; ++c) {
            const float v = hp[c];
            const float* wr = W + (l * GH + c) * 3;
            a0 = fmaf(v, wr[0], a0);
            a1 = fmaf(v, wr[1], a1);
            a2 = fmaf(v, wr[2], a2);
        }
    }
    if (*flag) {
        __hip_bfloat16* o = (__hip_bfloat16*)out;
        o[i*3+0] = __float2bfloat16(a0);
        o[i*3+1] = __float2bfloat16(a1);
        o[i*3+2] = __float2bfloat16(a2);
    } else {
        float* o = (float*)out;
        o[i*3+0] = a0; o[i*3+1] = a1; o[i*3+2] = a2;
    }
}

// ---------------------------------------------------------------------------
extern "C" void kernel_launch(void* const* d_in, const int* in_sizes, int n_in,
                              void* d_out, int out_size, void* d_ws, size_t ws_size,
                              hipStream_t stream)
{
    float* wsf  = (float*)d_ws;
    int* idxb   = (int*)(wsf + OFF_IDX);
    int* flagsb = (int*)(wsf + OFF_FLAGS);
    int* dflag  = (int*)(wsf + OFF_DFLAG);

    detect_kernel<<<1, 64, 0, stream>>>((const unsigned short*)d_in[0], dflag);

    const int segoff[9] = {OFF_XF, OFF_EMBW, OFF_EMBB, OFF_W1, OFF_B1,
                           OFF_W2, OFF_B2, OFF_OW, OFF_OB};
    const int segn[9]   = {GN*3, 3*GH, GH, GL*2*GH*GH, GL*GH,
                           GL*GH*GH, GL*GH, GL*GH*3, 3};
    for (int s = 0; s < 9; ++s)
        convert_kernel<<<(segn[s] + 255)/256, 256, 0, stream>>>(
            d_in[s], wsf + segoff[s], segn[s], dflag);

    embed_kernel<<<GN/256, 256, 0, stream>>>(
        wsf + OFF_XF, wsf + OFF_EMBW, wsf + OFF_EMBB, wsf + OFF_H);

    for (int l = 0; l < GL; ++l) {
        const float* hin = wsf + OFF_H + l*GN*HPS;
        float* hout      = wsf + OFF_H + (l+1)*GN*HPS;
        knn4_kernel<<<GN/RPB, NTHR, 0, stream>>>(hin, idxb, flagsb);
        rescue_kernel<<<GN/RPB, 64, 0, stream>>>(hin, flagsb, idxb);
        edgeconv_kernel<<<GN/64, 256, 0, stream>>>(hin, idxb,
            wsf + OFF_W1 + l*2*GH*GH, wsf + OFF_B1 + l*GH,
            wsf + OFF_W2 + l*GH*GH,  wsf + OFF_B2 + l*GH, hout);
    }

    out_kernel<<<GN/256, 256, 0, stream>>>(
        wsf + OFF_H + GN*HPS, wsf + OFF_OW, wsf + OFF_OB, d_out, dflag);
}

// Round 5
// 1216.936 us; speedup vs baseline: 2.5068x; 1.0442x over previous
//
#include <hip/hip_runtime.h>
#include <hip/hip_bf16.h>

#define GN 16384
#define GH 16
#define GK 16
#define GL 4
#define HPS 20            // padded h row: 16 features + sq + 3 pad (80 B, 16B-aligned)

// knn params
#define RPB 32            // rows per block
#define NTHR 1024         // 16 waves; 8 row-quads x 128 col-slots
#define CAP 160           // collect buffer capacity per row
#define BSTR 161          // buffer row stride (floats)
#define SSTR 264          // phase-1 sample-merge row stride
#define TILE_C 256        // columns per LDS tile
#define TILE_F (TILE_C*HPS)
#define LDS_TILE (2*RPB*BSTR + 2*RPB)   // tile offset in lds floats
#define LDS_TOT  (LDS_TILE + 2*TILE_F)  // 20608 floats = 80.5 KB (forces 1 blk/CU)

#define INFF __builtin_inff()

// workspace float-offsets
#define OFF_H     0
#define OFF_IDX   (5*GN*HPS)
#define OFF_FLAGS (OFF_IDX + GN*GK)
#define OFF_XF    (OFF_FLAGS + GN)
#define OFF_EMBW  (OFF_XF + GN*3)
#define OFF_EMBB  (OFF_EMBW + 3*GH)
#define OFF_W1    (OFF_EMBB + GH)
#define OFF_B1    (OFF_W1 + GL*2*GH*GH)
#define OFF_W2    (OFF_B1 + GL*GH)
#define OFF_B2    (OFF_W2 + GL*GH*GH)
#define OFF_OW    (OFF_B2 + GL*GH)
#define OFF_OB    (OFF_OW + GL*GH*3)
#define OFF_DFLAG (OFF_OB + 4)

// ---------------------------------------------------------------------------
__global__ void detect_kernel(const unsigned short* __restrict__ raw,
                              int* __restrict__ flag)
{
    if (threadIdx.x == 0 && blockIdx.x == 0) {
        int cnt = 0;
        for (int i = 0; i < 64; ++i) {
            unsigned int bits = ((unsigned int)raw[2*i]) << 16;
            float v = __uint_as_float(bits);
            float a = fabsf(v);
            if (a > 1e-4f && a < 50.f) ++cnt;
        }
        *flag = (cnt >= 32) ? 1 : 0;   // 1 = inputs are bf16
    }
}

__global__ void convert_kernel(const void* __restrict__ src,
                               float* __restrict__ dst, int n,
                               const int* __restrict__ flag)
{
    int i = blockIdx.x * 256 + threadIdx.x;
    if (i >= n) return;
    if (*flag)
        dst[i] = __bfloat162float(((const __hip_bfloat16*)src)[i]);
    else
        dst[i] = ((const float*)src)[i];
}

// ---------------------------------------------------------------------------
__device__ __forceinline__ float distt(const float hi[16], float sqi,
                                       const float* __restrict__ hj)
{
    float4 A = *(const float4*)(hj + 0);
    float4 B = *(const float4*)(hj + 4);
    float4 C = *(const float4*)(hj + 8);
    float4 D = *(const float4*)(hj + 12);
    float sqj = hj[16];
    float d0 = hi[0]*A.x;
    float d1 = hi[1]*A.y;
    d0 = fmaf(hi[2],  A.z, d0);  d1 = fmaf(hi[3],  A.w, d1);
    d0 = fmaf(hi[4],  B.x, d0);  d1 = fmaf(hi[5],  B.y, d1);
    d0 = fmaf(hi[6],  B.z, d0);  d1 = fmaf(hi[7],  B.w, d1);
    d0 = fmaf(hi[8],  C.x, d0);  d1 = fmaf(hi[9],  C.y, d1);
    d0 = fmaf(hi[10], C.z, d0);  d1 = fmaf(hi[11], C.w, d1);
    d0 = fmaf(hi[12], D.x, d0);  d1 = fmaf(hi[13], D.y, d1);
    d0 = fmaf(hi[14], D.z, d0);  d1 = fmaf(hi[15], D.w, d1);
    return fmaf(-2.f, d0 + d1, sqi + sqj);
}

#define LOAD_HI(ptr)                                                        \
    float hi[16]; float sqi;                                                \
    {                                                                       \
        const float* _hr = (ptr);                                           \
        float4 A = *(const float4*)(_hr + 0);                               \
        float4 B = *(const float4*)(_hr + 4);                               \
        float4 C = *(const float4*)(_hr + 8);                               \
        float4 D = *(const float4*)(_hr + 12);                              \
        hi[0]=A.x; hi[1]=A.y; hi[2]=A.z; hi[3]=A.w;                         \
        hi[4]=B.x; hi[5]=B.y; hi[6]=B.z; hi[7]=B.w;                         \
        hi[8]=C.x; hi[9]=C.y; hi[10]=C.z; hi[11]=C.w;                       \
        hi[12]=D.x; hi[13]=D.y; hi[14]=D.z; hi[15]=D.w;                     \
        sqi = _hr[16];                                                      \
    }

// ---------------------------------------------------------------------------
__global__ __launch_bounds__(256) void embed_kernel(
    const float* __restrict__ xf, const float* __restrict__ W,
    const float* __restrict__ b, float* __restrict__ h0)
{
    int i = blockIdx.x * 256 + threadIdx.x;
    float x0 = xf[i*3+0], x1 = xf[i*3+1], x2 = xf[i*3+2];
    float* orow = h0 + i * HPS;
    float sq = 0.f;
#pragma unroll
    for (int c = 0; c < GH; ++c) {
        float t = b[c];
        t = fmaf(x0, W[0*GH+c], t);
        t = fmaf(x1, W[1*GH+c], t);
        t = fmaf(x2, W[2*GH+c], t);
        t = fmaxf(t, 0.f);
        orow[c] = t;
        sq = fmaf(t, t, sq);
    }
    orow[16] = sq;
}

// ---------------------------------------------------------------------------
// Exact kNN: 2-phase threshold-collect; double-buffered LDS tiles;
// 4-row register blocking; 1 block/CU, ~120 VGPR (no spill).
__global__ __launch_bounds__(NTHR, 1) void knn5_kernel(
    const float* __restrict__ hp, int* __restrict__ idxout,
    int* __restrict__ flags)
{
    __shared__ float lds[LDS_TOT];
    float*    bufd = lds;
    int*      bufj = (int*)(lds + RPB*BSTR);
    unsigned* cnt  = (unsigned*)(lds + 2*RPB*BSTR);
    float*    tau  = lds + 2*RPB*BSTR + RPB;
    float*    tcur = lds + LDS_TILE;
    float*    tnxt = lds + LDS_TILE + TILE_F;

    const int tid = threadIdx.x;
    const int q   = tid & 7;            // row-quad 0..7 (rows q*4..q*4+3)
    const int s   = tid >> 3;           // col-slot 0..127
    const int r0  = blockIdx.x * RPB + q * 4;   // first global row of quad

    // ---- load 4 center rows into registers
    float hi[4][16]; float sqi[4];
#pragma unroll
    for (int rr = 0; rr < 4; ++rr) {
        const float* hr = hp + (r0 + rr) * HPS;
        float4 A = *(const float4*)(hr + 0);
        float4 B = *(const float4*)(hr + 4);
        float4 C = *(const float4*)(hr + 8);
        float4 D = *(const float4*)(hr + 12);
        hi[rr][0]=A.x; hi[rr][1]=A.y; hi[rr][2]=A.z; hi[rr][3]=A.w;
        hi[rr][4]=B.x; hi[rr][5]=B.y; hi[rr][6]=B.z; hi[rr][7]=B.w;
        hi[rr][8]=C.x; hi[rr][9]=C.y; hi[rr][10]=C.z; hi[rr][11]=C.w;
        hi[rr][12]=D.x; hi[rr][13]=D.y; hi[rr][14]=D.z; hi[rr][15]=D.w;
        sqi[rr] = hr[16];
    }

    // ---- staging constants (float4 units); tile = 256 cols x 5 float4
    const int c0 = tid / 5, f0 = tid - 5*c0;
    const bool has2 = tid < (TILE_C*5 - NTHR);          // 256 threads
    const int v1 = tid + NTHR;
    const int c1 = v1 / 5, f1 = v1 - 5*c1;
    const float4* hp4 = (const float4*)hp;
    const int o1a = 20*c0 + f0, o1b = 20*c1 + f1;       // phase-1 (stride-4 cols)
    const int o2a = 5*c0 + f0,  o2b = 5*c1 + f1;        // phase-2 (contiguous)

    // distance for 4 rows vs staged col; sets dd[0..3]
#define DIST4(hjp, jglob, dd)                                               \
    {                                                                       \
        const float* _hj = (hjp);                                           \
        float4 A = *(const float4*)(_hj + 0);                               \
        float4 B = *(const float4*)(_hj + 4);                               \
        float4 C = *(const float4*)(_hj + 8);                               \
        float4 D = *(const float4*)(_hj + 12);                              \
        float sqj = _hj[16];                                                \
        _Pragma("unroll")                                                   \
        for (int rr = 0; rr < 4; ++rr) {                                    \
            float d0 = hi[rr][0]*A.x;                                       \
            float d1 = hi[rr][1]*A.y;                                       \
            d0 = fmaf(hi[rr][2],  A.z, d0);  d1 = fmaf(hi[rr][3],  A.w, d1);\
            d0 = fmaf(hi[rr][4],  B.x, d0);  d1 = fmaf(hi[rr][5],  B.y, d1);\
            d0 = fmaf(hi[rr][6],  B.z, d0);  d1 = fmaf(hi[rr][7],  B.w, d1);\
            d0 = fmaf(hi[rr][8],  C.x, d0);  d1 = fmaf(hi[rr][9],  C.y, d1);\
            d0 = fmaf(hi[rr][10], C.z, d0);  d1 = fmaf(hi[rr][11], C.w, d1);\
            d0 = fmaf(hi[rr][12], D.x, d0);  d1 = fmaf(hi[rr][13], D.y, d1);\
            d0 = fmaf(hi[rr][14], D.z, d0);  d1 = fmaf(hi[rr][15], D.w, d1);\
            dd[rr] = fmaf(-2.f, d0 + d1, sqi[rr] + sqj);                    \
        }                                                                   \
        unsigned u = (unsigned)((jglob) - r0);                              \
        if (u < 4u) {                                                       \
            _Pragma("unroll")                                               \
            for (int rr = 0; rr < 4; ++rr)                                  \
                if (u == (unsigned)rr) dd[rr] = INFF;                       \
        }                                                                   \
    }

    // ---- phase 1: sample every 4th column; branchless per-row top-2 stream
    float m1[4], m2[4];
#pragma unroll
    for (int rr = 0; rr < 4; ++rr) { m1[rr] = INFF; m2[rr] = INFF; }
    {
        float4 ga, gb;
        ga = hp4[o1a];
        if (has2) gb = hp4[o1b];
        ((float4*)tcur)[tid] = ga;
        if (has2) ((float4*)tcur)[v1] = gb;
        for (int k = 0; k < 16; ++k) {
            __syncthreads();                    // tile tcur ready for all
            if (k + 1 < 16) {
                ga = hp4[5120*(k+1) + o1a];
                if (has2) gb = hp4[5120*(k+1) + o1b];
            }
#pragma unroll
            for (int cc = 0; cc < 2; ++cc) {
                const int lc = s + cc*128;
                const int j = 4*(256*k + lc);
                float dd[4];
                DIST4(tcur + lc*HPS, j, dd);
#pragma unroll
                for (int rr = 0; rr < 4; ++rr) {
                    float t = fmaxf(m1[rr], dd[rr]);
                    m1[rr] = fminf(m1[rr], dd[rr]);
                    m2[rr] = fminf(m2[rr], t);
                }
            }
            if (k + 1 < 16) {                   // write next tile under compute shadow
                ((float4*)tnxt)[tid] = ga;
                if (has2) ((float4*)tnxt)[v1] = gb;
            }
            float* tt = tcur; tcur = tnxt; tnxt = tt;
        }
    }
    __syncthreads();   // tile reads done; overlay sample-merge region
    // stash per-(thread,row) top-2 into buffer region for the row merge
#pragma unroll
    for (int rr = 0; rr < 4; ++rr) {
        lds[(q*4+rr)*SSTR + s*2 + 0] = m1[rr];
        lds[(q*4+rr)*SSTR + s*2 + 1] = m2[rr];
    }
    __syncthreads();

    // ---- phase 1b: per-row merge (32 lanes/row): tau = 16th smallest sample
    const int mr = tid >> 5, g = tid & 31;
    float s8[8];
    {
        float4 u0 = *(const float4*)(lds + mr*SSTR + g*8);
        float4 u1 = *(const float4*)(lds + mr*SSTR + g*8 + 4);
        s8[0]=u0.x; s8[1]=u0.y; s8[2]=u0.z; s8[3]=u0.w;
        s8[4]=u1.x; s8[5]=u1.y; s8[6]=u1.z; s8[7]=u1.w;
    }
    float tval = INFF;
#pragma unroll
    for (int k = 0; k < 16; ++k) {
        float md = s8[0]; int ms = 0;
#pragma unroll
        for (int e = 1; e < 8; ++e) { bool cs = (s8[e] < md); md = cs ? s8[e] : md; ms = cs ? e : ms; }
        float rv = md; int rl = g;
#pragma unroll
        for (int m = 1; m <= 16; m <<= 1) {
            float ov = __shfl_xor(rv, m, 32);
            int   ol = __shfl_xor(rl, m, 32);
            bool cs = (ov < rv) || (ov == rv && ol < rl);
            rv = cs ? ov : rv; rl = cs ? ol : rl;
        }
        if (rl == g) {
#pragma unroll
            for (int e = 0; e < 8; ++e) if (e == ms) s8[e] = INFF;
        }
        tval = rv;
    }
    if (g == 0) tau[mr] = tval;
    if (tid < RPB) cnt[tid] = 0;
    __syncthreads();

    // ---- phase 2: full scan via tiles, append d <= tau (identical arithmetic
    // to phase 1 -> count >= 16 guaranteed).
    float tau4[4];
#pragma unroll
    for (int rr = 0; rr < 4; ++rr) tau4[rr] = tau[q*4+rr];
    {
        float4 ga, gb;
        ga = hp4[o2a];
        if (has2) gb = hp4[o2b];
        ((float4*)tcur)[tid] = ga;
        if (has2) ((float4*)tcur)[v1] = gb;
        for (int k = 0; k < GN/TILE_C; ++k) {      // 64 tiles
            __syncthreads();
            if (k + 1 < GN/TILE_C) {
                ga = hp4[1280*(k+1) + o2a];
                if (has2) gb = hp4[1280*(k+1) + o2b];
            }
#pragma unroll
            for (int cc = 0; cc < 2; ++cc) {
                const int lc = s + cc*128;
                const int j = 256*k + lc;
                float dd[4];
                DIST4(tcur + lc*HPS, j, dd);
                bool p0 = dd[0] <= tau4[0], p1 = dd[1] <= tau4[1];
                bool p2 = dd[2] <= tau4[2], p3 = dd[3] <= tau4[3];
                if (p0 | p1 | p2 | p3) {
#pragma unroll
                    for (int rr = 0; rr < 4; ++rr) {
                        if (dd[rr] <= tau4[rr]) {
                            unsigned pos = atomicAdd(&cnt[q*4+rr], 1u);
                            if (pos < CAP) {
                                bufd[(q*4+rr)*BSTR + pos] = dd[rr];
                                bufj[(q*4+rr)*BSTR + pos] = j;
                            }
                        }
                    }
                }
            }
            if (k + 1 < GN/TILE_C) {
                ((float4*)tnxt)[tid] = ga;
                if (has2) ((float4*)tnxt)[v1] = gb;
            }
            float* tt = tcur; tcur = tnxt; tnxt = tt;
        }
    }
    __syncthreads();

    // ---- phase 3: exact top-16 of buffer per row (32 lanes/row), (d,j) order
    const unsigned c   = cnt[mr];
    const unsigned lim = c < CAP ? c : CAP;
    float sd[5]; int sj[5];
#pragma unroll
    for (int e = 0; e < 5; ++e) {
        unsigned p = (unsigned)g + 32u*e;
        bool v = p < lim;
        sd[e] = v ? bufd[mr*BSTR + p] : INFF;
        sj[e] = v ? bufj[mr*BSTR + p] : 0x7fffffff;
    }
    const int rowg = blockIdx.x * RPB + mr;
#pragma unroll
    for (int k = 0; k < GK; ++k) {
        float md = sd[0]; int mj = sj[0]; int ms = 0;
#pragma unroll
        for (int e = 1; e < 5; ++e) {
            bool cs = (sd[e] < md) || (sd[e] == md && sj[e] < mj);
            md = cs ? sd[e] : md; mj = cs ? sj[e] : mj; ms = cs ? e : ms;
        }
        float rd = md; int rj = mj;
#pragma unroll
        for (int m = 1; m <= 16; m <<= 1) {
            float od = __shfl_xor(rd, m, 32);
            int   oj = __shfl_xor(rj, m, 32);
            bool cs = (od < rd) || (od == rd && oj < rj);
            rd = cs ? od : rd; rj = cs ? oj : rj;
        }
        if (g == 0) idxout[rowg*GK + k] = rj;
        if (rd == md && rj == mj) {
#pragma unroll
            for (int e = 0; e < 5; ++e) if (e == ms) { sd[e] = INFF; sj[e] = 0x7fffffff; }
        }
    }
    if (g == 0) flags[rowg] = (c > CAP || c < 16u) ? 1 : 0;
#undef DIST4
}

// ---------------------------------------------------------------------------
// Exact full-scan fallback for rows whose buffer overflowed (P ~ 1e-6/row).
__global__ __launch_bounds__(64) void rescue_kernel(
    const float* __restrict__ hp, const int* __restrict__ flags,
    int* __restrict__ idxout)
{
    const int lane = threadIdx.x;
    const int r0 = blockIdx.x * RPB;
    int f = (lane < RPB) ? flags[r0 + lane] : 0;
    if (__ballot(f != 0) == 0ull) return;
    for (int rr = 0; rr < RPB; ++rr) {
        if (flags[r0 + rr] == 0) continue;
        const int row = r0 + rr;
        LOAD_HI(hp + row * HPS);
        float topd[GK]; int topi[GK];
#pragma unroll
        for (int s = 0; s < GK; ++s) { topd[s] = INFF; topi[s] = -1; }
        float mx = INFF; int mxs = 0;
        for (int s = 0; s < GN/64; ++s) {
            int j = lane + (s << 6);
            float d = distt(hi, sqi, hp + j * HPS);
            if (j == row) d = INFF;
            if (d < mx) {
#pragma unroll
                for (int e = 0; e < GK; ++e) { bool cs = (e == mxs); topd[e] = cs ? d : topd[e]; topi[e] = cs ? j : topi[e]; }
                mx = topd[0]; mxs = 0;
#pragma unroll
                for (int e = 1; e < GK; ++e) { bool cs = (topd[e] >= mx); mx = cs ? topd[e] : mx; mxs = cs ? e : mxs; }
            }
        }
#pragma unroll
        for (int t = 0; t < GK; ++t) {
            float md = topd[0]; int mj = topi[0]; int ms = 0;
#pragma unroll
            for (int e = 1; e < GK; ++e) {
                bool cs = (topd[e] < md) || (topd[e] == md && topi[e] < mj);
                md = cs ? topd[e] : md; mj = cs ? topi[e] : mj; ms = cs ? e : ms;
            }
            float rd = md; int rj = mj;
#pragma unroll
            for (int m = 1; m <= 32; m <<= 1) {
                float od = __shfl_xor(rd, m, 64);
                int   oj = __shfl_xor(rj, m, 64);
                bool cs = (od < rd) || (od == rd && oj < rj);
                rd = cs ? od : rd; rj = cs ? oj : rj;
            }
            if (lane == 0) idxout[row*GK + t] = rj;
            if (rd == md && rj == mj) {
#pragma unroll
                for (int e = 0; e < GK; ++e) if (e == ms) { topd[e] = INFF; topi[e] = 0x7fffffff; }
            }
        }
    }
}

// ---------------------------------------------------------------------------
__global__ __launch_bounds__(256) void edgeconv_kernel(
    const float* __restrict__ hin, const int* __restrict__ idx,
    const float* __restrict__ W1, const float* __restrict__ b1,
    const float* __restrict__ W2, const float* __restrict__ b2,
    float* __restrict__ hout)
{
    __shared__ float sW1[2*GH*GH], sW2[GH*GH], sb1[GH], sb2[GH];
    const int tid = threadIdx.x;
    for (int t = tid; t < 2*GH*GH; t += 256) sW1[t] = W1[t];
    for (int t = tid; t < GH*GH;  t += 256) sW2[t] = W2[t];
    if (tid < GH) { sb1[tid] = b1[tid]; sb2[tid] = b2[tid]; }
    __syncthreads();

    const int t4 = tid & 3;
    const int i = blockIdx.x * 64 + (tid >> 2);

    LOAD_HI(hin + i * HPS);
    (void)sqi;
    float ci[GH];
#pragma unroll
    for (int c = 0; c < GH; ++c) {
        float s = sb1[c];
#pragma unroll
        for (int d = 0; d < GH; ++d) s = fmaf(hi[d], sW1[d*GH+c], s);
        ci[c] = s;
    }
    float acc[GH];
#pragma unroll
    for (int c = 0; c < GH; ++c) acc[c] = 0.f;

    const int4 jj = *(const int4*)(idx + i*GK + t4*4);
    const int js[4] = { jj.x, jj.y, jj.z, jj.w };
#pragma unroll
    for (int nn = 0; nn < 4; ++nn) {
        const int j = js[nn];
        float dj[GH];
        {
            const float* hv = hin + j * HPS;
            float4 A = *(const float4*)(hv + 0);
            float4 B = *(const float4*)(hv + 4);
            float4 C = *(const float4*)(hv + 8);
            float4 D = *(const float4*)(hv + 12);
            dj[0]=A.x-hi[0]; dj[1]=A.y-hi[1]; dj[2]=A.z-hi[2]; dj[3]=A.w-hi[3];
            dj[4]=B.x-hi[4]; dj[5]=B.y-hi[5]; dj[6]=B.z-hi[6]; dj[7]=B.w-hi[7];
            dj[8]=C.x-hi[8]; dj[9]=C.y-hi[9]; dj[10]=C.z-hi[10]; dj[11]=C.w-hi[11];
            dj[12]=D.x-hi[12]; dj[13]=D.y-hi[13]; dj[14]=D.z-hi[14]; dj[15]=D.w-hi[15];
        }
        float msg[GH];
#pragma unroll
        for (int c = 0; c < GH; ++c) {
            float s = ci[c];
#pragma unroll
            for (int d = 0; d < GH; ++d) s = fmaf(dj[d], sW1[(GH+d)*GH+c], s);
            msg[c] = fmaxf(s, 0.f);
        }
#pragma unroll
        for (int c2 = 0; c2 < GH; ++c2) {
            float s = acc[c2];
#pragma unroll
            for (int c = 0; c < GH; ++c) s = fmaf(msg[c], sW2[c*GH+c2], s);
            acc[c2] = s;
        }
    }
#pragma unroll
    for (int c = 0; c < GH; ++c) {
        acc[c] += __shfl_xor(acc[c], 1);
        acc[c] += __shfl_xor(acc[c], 2);
    }
    if (t4 == 0) {
        float* orow = hout + i * HPS;
        float sq = 0.f;
#pragma unroll
        for (int c = 0; c < GH; ++c) {
            float v = acc[c] * (1.f/16.f) + sb2[c];
            orow[c] = v;
            sq = fmaf(v, v, sq);
        }
        orow[16] = sq;
    }
}

// ---------------------------------------------------------------------------
__global__ __launch_bounds__(256) void out_kernel(
    const float* __restrict__ hbase, const float* __restrict__ W,
    const float* __restrict__ b, void* __restrict__ out,
    const int* __restrict__ flag)
{
    int i = blockIdx.x * 256 + threadIdx.x;
    float a0 = b[0], a1 = b[1], a2 = b[2];
#pragma unroll
    for (int l = 0; l < GL; ++l) {
        const float* hp = hbase + l * GN * HPS + i * HPS;
#pragma unroll
        for (int c = 0; c < GH; ++c) {
            const float v = hp[c];
            const float* wr = W + (l * GH + c) * 3;
            a0 = fmaf(v, wr[0], a0);
            a1 = fmaf(v, wr[1], a1);
            a2 = fmaf(v, wr[2], a2);
        }
    }
    if (*flag) {
        __hip_bfloat16* o = (__hip_bfloat16*)out;
        o[i*3+0] = __float2bfloat16(a0);
        o[i*3+1] = __float2bfloat16(a1);
        o[i*3+2] = __float2bfloat16(a2);
    } else {
        float* o = (float*)out;
        o[i*3+0] = a0; o[i*3+1] = a1; o[i*3+2] = a2;
    }
}

// ---------------------------------------------------------------------------
extern "C" void kernel_launch(void* const* d_in, const int* in_sizes, int n_in,
                              void* d_out, int out_size, void* d_ws, size_t ws_size,
                              hipStream_t stream)
{
    float* wsf  = (float*)d_ws;
    int* idxb   = (int*)(wsf + OFF_IDX);
    int* flagsb = (int*)(wsf + OFF_FLAGS);
    int* dflag  = (int*)(wsf + OFF_DFLAG);

    detect_kernel<<<1, 64, 0, stream>>>((const unsigned short*)d_in[0], dflag);

    const int segoff[9] = {OFF_XF, OFF_EMBW, OFF_EMBB, OFF_W1, OFF_B1,
                           OFF_W2, OFF_B2, OFF_OW, OFF_OB};
    const int segn[9]   = {GN*3, 3*GH, GH, GL*2*GH*GH, GL*GH,
                           GL*GH*GH, GL*GH, GL*GH*3, 3};
    for (int s = 0; s < 9; ++s)
        convert_kernel<<<(segn[s] + 255)/256, 256, 0, stream>>>(
            d_in[s], wsf + segoff[s], segn[s], dflag);

    embed_kernel<<<GN/256, 256, 0, stream>>>(
        wsf + OFF_XF, wsf + OFF_EMBW, wsf + OFF_EMBB, wsf + OFF_H);

    for (int l = 0; l < GL; ++l) {
        const float* hin = wsf + OFF_H + l*GN*HPS;
        float* hout      = wsf + OFF_H + (l+1)*GN*HPS;
        knn5_kernel<<<GN/RPB, NTHR, 0, stream>>>(hin, idxb, flagsb);
        rescue_kernel<<<GN/RPB, 64, 0, stream>>>(hin, flagsb, idxb);
        edgeconv_kernel<<<GN/64, 256, 0, stream>>>(hin, idxb,
            wsf + OFF_W1 + l*2*GH*GH, wsf + OFF_B1 + l*GH,
            wsf + OFF_W2 + l*GH*GH,  wsf + OFF_B2 + l*GH, hout);
    }

    out_kernel<<<GN/256, 256, 0, stream>>>(
        wsf + OFF_H + GN*HPS, wsf + OFF_OW, wsf + OFF_OB, d_out, dflag);
}

// Round 6
// 1211.108 us; speedup vs baseline: 2.5189x; 1.0048x over previous
//
#include <hip/hip_runtime.h>
#include <hip/hip_bf16.h>

#define GN 16384
#define GH 16
#define GK 16
#define GL 4
#define HPS 20            // padded h row: 16 features + sq + 3 pad (80 B, 16B-aligned)

// knn params
#define RPB 32            // rows per block
#define NTHR 1024         // 16 waves; 8 row-quads x 128 col-slots
#define CAP 160           // collect buffer capacity per row
#define BSTR 161          // buffer row stride (floats)
#define SSTR 264          // phase-1 sample-merge row stride
#define TILE_C 256        // columns per LDS tile
#define TILE_F (TILE_C*HPS)
#define LDS_TILE (2*RPB*BSTR + 2*RPB)   // tile offset in lds floats
#define LDS_TOT  (LDS_TILE + 2*TILE_F)  // 20608 floats = 80.5 KB (1 blk/CU)

#define INFF __builtin_inff()

// workspace float-offsets
#define OFF_H     0
#define OFF_IDX   (5*GN*HPS)
#define OFF_FLAGS (OFF_IDX + GN*GK)
#define OFF_XF    (OFF_FLAGS + GN)
#define OFF_EMBW  (OFF_XF + GN*3)
#define OFF_EMBB  (OFF_EMBW + 3*GH)
#define OFF_W1    (OFF_EMBB + GH)
#define OFF_B1    (OFF_W1 + GL*2*GH*GH)
#define OFF_W2    (OFF_B1 + GL*GH)
#define OFF_B2    (OFF_W2 + GL*GH*GH)
#define OFF_OW    (OFF_B2 + GL*GH)
#define OFF_OB    (OFF_OW + GL*GH*3)
#define OFF_DFLAG (OFF_OB + 4)

// ---------------------------------------------------------------------------
__global__ void detect_kernel(const unsigned short* __restrict__ raw,
                              int* __restrict__ flag)
{
    if (threadIdx.x == 0 && blockIdx.x == 0) {
        int cnt = 0;
        for (int i = 0; i < 64; ++i) {
            unsigned int bits = ((unsigned int)raw[2*i]) << 16;
            float v = __uint_as_float(bits);
            float a = fabsf(v);
            if (a > 1e-4f && a < 50.f) ++cnt;
        }
        *flag = (cnt >= 32) ? 1 : 0;   // 1 = inputs are bf16
    }
}

__global__ void convert_kernel(const void* __restrict__ src,
                               float* __restrict__ dst, int n,
                               const int* __restrict__ flag)
{
    int i = blockIdx.x * 256 + threadIdx.x;
    if (i >= n) return;
    if (*flag)
        dst[i] = __bfloat162float(((const __hip_bfloat16*)src)[i]);
    else
        dst[i] = ((const float*)src)[i];
}

// ---------------------------------------------------------------------------
__device__ __forceinline__ float distt(const float hi[16], float sqi,
                                       const float* __restrict__ hj)
{
    float4 A = *(const float4*)(hj + 0);
    float4 B = *(const float4*)(hj + 4);
    float4 C = *(const float4*)(hj + 8);
    float4 D = *(const float4*)(hj + 12);
    float sqj = hj[16];
    float d0 = hi[0]*A.x;
    float d1 = hi[1]*A.y;
    d0 = fmaf(hi[2],  A.z, d0);  d1 = fmaf(hi[3],  A.w, d1);
    d0 = fmaf(hi[4],  B.x, d0);  d1 = fmaf(hi[5],  B.y, d1);
    d0 = fmaf(hi[6],  B.z, d0);  d1 = fmaf(hi[7],  B.w, d1);
    d0 = fmaf(hi[8],  C.x, d0);  d1 = fmaf(hi[9],  C.y, d1);
    d0 = fmaf(hi[10], C.z, d0);  d1 = fmaf(hi[11], C.w, d1);
    d0 = fmaf(hi[12], D.x, d0);  d1 = fmaf(hi[13], D.y, d1);
    d0 = fmaf(hi[14], D.z, d0);  d1 = fmaf(hi[15], D.w, d1);
    return fmaf(-2.f, d0 + d1, sqi + sqj);
}

#define LOAD_HI(ptr)                                                        \
    float hi[16]; float sqi;                                                \
    {                                                                       \
        const float* _hr = (ptr);                                           \
        float4 A = *(const float4*)(_hr + 0);                               \
        float4 B = *(const float4*)(_hr + 4);                               \
        float4 C = *(const float4*)(_hr + 8);                               \
        float4 D = *(const float4*)(_hr + 12);                              \
        hi[0]=A.x; hi[1]=A.y; hi[2]=A.z; hi[3]=A.w;                         \
        hi[4]=B.x; hi[5]=B.y; hi[6]=B.z; hi[7]=B.w;                         \
        hi[8]=C.x; hi[9]=C.y; hi[10]=C.z; hi[11]=C.w;                       \
        hi[12]=D.x; hi[13]=D.y; hi[14]=D.z; hi[15]=D.w;                     \
        sqi = _hr[16];                                                      \
    }

// ---------------------------------------------------------------------------
__global__ __launch_bounds__(256) void embed_kernel(
    const float* __restrict__ xf, const float* __restrict__ W,
    const float* __restrict__ b, float* __restrict__ h0)
{
    int i = blockIdx.x * 256 + threadIdx.x;
    float x0 = xf[i*3+0], x1 = xf[i*3+1], x2 = xf[i*3+2];
    float* orow = h0 + i * HPS;
    float sq = 0.f;
#pragma unroll
    for (int c = 0; c < GH; ++c) {
        float t = b[c];
        t = fmaf(x0, W[0*GH+c], t);
        t = fmaf(x1, W[1*GH+c], t);
        t = fmaf(x2, W[2*GH+c], t);
        t = fmaxf(t, 0.f);
        orow[c] = t;
        sq = fmaf(t, t, sq);
    }
    orow[16] = sq;
}

// ---------------------------------------------------------------------------
// Exact kNN: 2-phase threshold-collect; double-buffered LDS tiles;
// 4-row register blocking. 1024-thr block == 4 waves/SIMD exactly, so pin
// waves_per_eu to (4,4): VGPR budget 128 (no 8-wave heuristic -> no AGPR
// copies / scratch spill of hi[4][16]).
__global__ __attribute__((amdgpu_flat_work_group_size(NTHR, NTHR),
                          amdgpu_waves_per_eu(4, 4)))
void knn6_kernel(
    const float* __restrict__ hp, int* __restrict__ idxout,
    int* __restrict__ flags)
{
    __shared__ float lds[LDS_TOT];
    float*    bufd = lds;
    int*      bufj = (int*)(lds + RPB*BSTR);
    unsigned* cnt  = (unsigned*)(lds + 2*RPB*BSTR);
    float*    tau  = lds + 2*RPB*BSTR + RPB;
    float*    tcur = lds + LDS_TILE;
    float*    tnxt = lds + LDS_TILE + TILE_F;

    const int tid = threadIdx.x;
    const int q   = tid & 7;            // row-quad 0..7 (rows q*4..q*4+3)
    const int s   = tid >> 3;           // col-slot 0..127
    const int r0  = blockIdx.x * RPB + q * 4;   // first global row of quad

    // ---- load 4 center rows into registers
    float hi[4][16]; float sqi[4];
#pragma unroll
    for (int rr = 0; rr < 4; ++rr) {
        const float* hr = hp + (r0 + rr) * HPS;
        float4 A = *(const float4*)(hr + 0);
        float4 B = *(const float4*)(hr + 4);
        float4 C = *(const float4*)(hr + 8);
        float4 D = *(const float4*)(hr + 12);
        hi[rr][0]=A.x; hi[rr][1]=A.y; hi[rr][2]=A.z; hi[rr][3]=A.w;
        hi[rr][4]=B.x; hi[rr][5]=B.y; hi[rr][6]=B.z; hi[rr][7]=B.w;
        hi[rr][8]=C.x; hi[rr][9]=C.y; hi[rr][10]=C.z; hi[rr][11]=C.w;
        hi[rr][12]=D.x; hi[rr][13]=D.y; hi[rr][14]=D.z; hi[rr][15]=D.w;
        sqi[rr] = hr[16];
    }

    // ---- staging constants (float4 units); tile = 256 cols x 5 float4
    const int c0 = tid / 5, f0 = tid - 5*c0;
    const bool has2 = tid < (TILE_C*5 - NTHR);          // 256 threads
    const int v1 = tid + NTHR;
    const int c1 = v1 / 5, f1 = v1 - 5*c1;
    const float4* hp4 = (const float4*)hp;
    const int o1a = 20*c0 + f0, o1b = 20*c1 + f1;       // phase-1 (stride-4 cols)
    const int o2a = 5*c0 + f0,  o2b = 5*c1 + f1;        // phase-2 (contiguous)

    // distance for 4 rows vs staged col; sets dd[0..3]
#define DIST4(hjp, jglob, dd)                                               \
    {                                                                       \
        const float* _hj = (hjp);                                           \
        float4 A = *(const float4*)(_hj + 0);                               \
        float4 B = *(const float4*)(_hj + 4);                               \
        float4 C = *(const float4*)(_hj + 8);                               \
        float4 D = *(const float4*)(_hj + 12);                              \
        float sqj = _hj[16];                                                \
        _Pragma("unroll")                                                   \
        for (int rr = 0; rr < 4; ++rr) {                                    \
            float d0 = hi[rr][0]*A.x;                                       \
            float d1 = hi[rr][1]*A.y;                                       \
            d0 = fmaf(hi[rr][2],  A.z, d0);  d1 = fmaf(hi[rr][3],  A.w, d1);\
            d0 = fmaf(hi[rr][4],  B.x, d0);  d1 = fmaf(hi[rr][5],  B.y, d1);\
            d0 = fmaf(hi[rr][6],  B.z, d0);  d1 = fmaf(hi[rr][7],  B.w, d1);\
            d0 = fmaf(hi[rr][8],  C.x, d0);  d1 = fmaf(hi[rr][9],  C.y, d1);\
            d0 = fmaf(hi[rr][10], C.z, d0);  d1 = fmaf(hi[rr][11], C.w, d1);\
            d0 = fmaf(hi[rr][12], D.x, d0);  d1 = fmaf(hi[rr][13], D.y, d1);\
            d0 = fmaf(hi[rr][14], D.z, d0);  d1 = fmaf(hi[rr][15], D.w, d1);\
            dd[rr] = fmaf(-2.f, d0 + d1, sqi[rr] + sqj);                    \
        }                                                                   \
        unsigned u = (unsigned)((jglob) - r0);                              \
        if (u < 4u) {                                                       \
            _Pragma("unroll")                                               \
            for (int rr = 0; rr < 4; ++rr)                                  \
                if (u == (unsigned)rr) dd[rr] = INFF;                       \
        }                                                                   \
    }

    // ---- phase 1: sample every 4th column; branchless per-row top-2 stream
    float m1[4], m2[4];
#pragma unroll
    for (int rr = 0; rr < 4; ++rr) { m1[rr] = INFF; m2[rr] = INFF; }
    {
        float4 ga, gb;
        ga = hp4[o1a];
        if (has2) gb = hp4[o1b];
        ((float4*)tcur)[tid] = ga;
        if (has2) ((float4*)tcur)[v1] = gb;
        for (int k = 0; k < 16; ++k) {
            __syncthreads();                    // tile tcur ready for all
            if (k + 1 < 16) {
                ga = hp4[5120*(k+1) + o1a];
                if (has2) gb = hp4[5120*(k+1) + o1b];
            }
#pragma unroll
            for (int cc = 0; cc < 2; ++cc) {
                const int lc = s + cc*128;
                const int j = 4*(256*k + lc);
                float dd[4];
                DIST4(tcur + lc*HPS, j, dd);
#pragma unroll
                for (int rr = 0; rr < 4; ++rr) {
                    float t = fmaxf(m1[rr], dd[rr]);
                    m1[rr] = fminf(m1[rr], dd[rr]);
                    m2[rr] = fminf(m2[rr], t);
                }
            }
            if (k + 1 < 16) {                   // write next tile under compute shadow
                ((float4*)tnxt)[tid] = ga;
                if (has2) ((float4*)tnxt)[v1] = gb;
            }
            float* tt = tcur; tcur = tnxt; tnxt = tt;
        }
    }
    __syncthreads();   // tile reads done; overlay sample-merge region
    // stash per-(thread,row) top-2 into buffer region for the row merge
#pragma unroll
    for (int rr = 0; rr < 4; ++rr) {
        lds[(q*4+rr)*SSTR + s*2 + 0] = m1[rr];
        lds[(q*4+rr)*SSTR + s*2 + 1] = m2[rr];
    }
    __syncthreads();

    // ---- phase 1b: per-row merge (32 lanes/row): tau = 16th smallest sample
    const int mr = tid >> 5, g = tid & 31;
    float s8[8];
    {
        float4 u0 = *(const float4*)(lds + mr*SSTR + g*8);
        float4 u1 = *(const float4*)(lds + mr*SSTR + g*8 + 4);
        s8[0]=u0.x; s8[1]=u0.y; s8[2]=u0.z; s8[3]=u0.w;
        s8[4]=u1.x; s8[5]=u1.y; s8[6]=u1.z; s8[7]=u1.w;
    }
    float tval = INFF;
#pragma unroll
    for (int k = 0; k < 16; ++k) {
        float md = s8[0]; int ms = 0;
#pragma unroll
        for (int e = 1; e < 8; ++e) { bool cs = (s8[e] < md); md = cs ? s8[e] : md; ms = cs ? e : ms; }
        float rv = md; int rl = g;
#pragma unroll
        for (int m = 1; m <= 16; m <<= 1) {
            float ov = __shfl_xor(rv, m, 32);
            int   ol = __shfl_xor(rl, m, 32);
            bool cs = (ov < rv) || (ov == rv && ol < rl);
            rv = cs ? ov : rv; rl = cs ? ol : rl;
        }
        if (rl == g) {
#pragma unroll
            for (int e = 0; e < 8; ++e) if (e == ms) s8[e] = INFF;
        }
        tval = rv;
    }
    if (g == 0) tau[mr] = tval;
    if (tid < RPB) cnt[tid] = 0;
    __syncthreads();

    // ---- phase 2: full scan via tiles, append d <= tau (identical arithmetic
    // to phase 1 -> count >= 16 guaranteed).
    float tau4[4];
#pragma unroll
    for (int rr = 0; rr < 4; ++rr) tau4[rr] = tau[q*4+rr];
    {
        float4 ga, gb;
        ga = hp4[o2a];
        if (has2) gb = hp4[o2b];
        ((float4*)tcur)[tid] = ga;
        if (has2) ((float4*)tcur)[v1] = gb;
        for (int k = 0; k < GN/TILE_C; ++k) {      // 64 tiles
            __syncthreads();
            if (k + 1 < GN/TILE_C) {
                ga = hp4[1280*(k+1) + o2a];
                if (has2) gb = hp4[1280*(k+1) + o2b];
            }
#pragma unroll
            for (int cc = 0; cc < 2; ++cc) {
                const int lc = s + cc*128;
                const int j = 256*k + lc;
                float dd[4];
                DIST4(tcur + lc*HPS, j, dd);
                bool p0 = dd[0] <= tau4[0], p1 = dd[1] <= tau4[1];
                bool p2 = dd[2] <= tau4[2], p3 = dd[3] <= tau4[3];
                if (p0 | p1 | p2 | p3) {
#pragma unroll
                    for (int rr = 0; rr < 4; ++rr) {
                        if (dd[rr] <= tau4[rr]) {
                            unsigned pos = atomicAdd(&cnt[q*4+rr], 1u);
                            if (pos < CAP) {
                                bufd[(q*4+rr)*BSTR + pos] = dd[rr];
                                bufj[(q*4+rr)*BSTR + pos] = j;
                            }
                        }
                    }
                }
            }
            if (k + 1 < GN/TILE_C) {
                ((float4*)tnxt)[tid] = ga;
                if (has2) ((float4*)tnxt)[v1] = gb;
            }
            float* tt = tcur; tcur = tnxt; tnxt = tt;
        }
    }
    __syncthreads();

    // ---- phase 3: exact top-16 of buffer per row (32 lanes/row), (d,j) order
    const unsigned c   = cnt[mr];
    const unsigned lim = c < CAP ? c : CAP;
    float sd[5]; int sj[5];
#pragma unroll
    for (int e = 0; e < 5; ++e) {
        unsigned p = (unsigned)g + 32u*e;
        bool v = p < lim;
        sd[e] = v ? bufd[mr*BSTR + p] : INFF;
        sj[e] = v ? bufj[mr*BSTR + p] : 0x7fffffff;
    }
    const int rowg = blockIdx.x * RPB + mr;
#pragma unroll
    for (int k = 0; k < GK; ++k) {
        float md = sd[0]; int mj = sj[0]; int ms = 0;
#pragma unroll
        for (int e = 1; e < 5; ++e) {
            bool cs = (sd[e] < md) || (sd[e] == md && sj[e] < mj);
            md = cs ? sd[e] : md; mj = cs ? sj[e] : mj; ms = cs ? e : ms;
        }
        float rd = md; int rj = mj;
#pragma unroll
        for (int m = 1; m <= 16; m <<= 1) {
            float od = __shfl_xor(rd, m, 32);
            int   oj = __shfl_xor(rj, m, 32);
            bool cs = (od < rd) || (od == rd && oj < rj);
            rd = cs ? od : rd; rj = cs ? oj : rj;
        }
        if (g == 0) idxout[rowg*GK + k] = rj;
        if (rd == md && rj == mj) {
#pragma unroll
            for (int e = 0; e < 5; ++e) if (e == ms) { sd[e] = INFF; sj[e] = 0x7fffffff; }
        }
    }
    if (g == 0) flags[rowg] = (c > CAP || c < 16u) ? 1 : 0;
#undef DIST4
}

// ---------------------------------------------------------------------------
// Exact full-scan fallback for rows whose buffer overflowed (P ~ 1e-6/row).
__global__ __launch_bounds__(64) void rescue_kernel(
    const float* __restrict__ hp, const int* __restrict__ flags,
    int* __restrict__ idxout)
{
    const int lane = threadIdx.x;
    const int r0 = blockIdx.x * RPB;
    int f = (lane < RPB) ? flags[r0 + lane] : 0;
    if (__ballot(f != 0) == 0ull) return;
    for (int rr = 0; rr < RPB; ++rr) {
        if (flags[r0 + rr] == 0) continue;
        const int row = r0 + rr;
        LOAD_HI(hp + row * HPS);
        float topd[GK]; int topi[GK];
#pragma unroll
        for (int s = 0; s < GK; ++s) { topd[s] = INFF; topi[s] = -1; }
        float mx = INFF; int mxs = 0;
        for (int s = 0; s < GN/64; ++s) {
            int j = lane + (s << 6);
            float d = distt(hi, sqi, hp + j * HPS);
            if (j == row) d = INFF;
            if (d < mx) {
#pragma unroll
                for (int e = 0; e < GK; ++e) { bool cs = (e == mxs); topd[e] = cs ? d : topd[e]; topi[e] = cs ? j : topi[e]; }
                mx = topd[0]; mxs = 0;
#pragma unroll
                for (int e = 1; e < GK; ++e) { bool cs = (topd[e] >= mx); mx = cs ? topd[e] : mx; mxs = cs ? e : mxs; }
            }
        }
#pragma unroll
        for (int t = 0; t < GK; ++t) {
            float md = topd[0]; int mj = topi[0]; int ms = 0;
#pragma unroll
            for (int e = 1; e < GK; ++e) {
                bool cs = (topd[e] < md) || (topd[e] == md && topi[e] < mj);
                md = cs ? topd[e] : md; mj = cs ? topi[e] : mj; ms = cs ? e : ms;
            }
            float rd = md; int rj = mj;
#pragma unroll
            for (int m = 1; m <= 32; m <<= 1) {
                float od = __shfl_xor(rd, m, 64);
                int   oj = __shfl_xor(rj, m, 64);
                bool cs = (od < rd) || (od == rd && oj < rj);
                rd = cs ? od : rd; rj = cs ? oj : rj;
            }
            if (lane == 0) idxout[row*GK + t] = rj;
            if (rd == md && rj == mj) {
#pragma unroll
                for (int e = 0; e < GK; ++e) if (e == ms) { topd[e] = INFF; topi[e] = 0x7fffffff; }
            }
        }
    }
}

// ---------------------------------------------------------------------------
__global__ __launch_bounds__(256) void edgeconv_kernel(
    const float* __restrict__ hin, const int* __restrict__ idx,
    const float* __restrict__ W1, const float* __restrict__ b1,
    const float* __restrict__ W2, const float* __restrict__ b2,
    float* __restrict__ hout)
{
    __shared__ float sW1[2*GH*GH], sW2[GH*GH], sb1[GH], sb2[GH];
    const int tid = threadIdx.x;
    for (int t = tid; t < 2*GH*GH; t += 256) sW1[t] = W1[t];
    for (int t = tid; t < GH*GH;  t += 256) sW2[t] = W2[t];
    if (tid < GH) { sb1[tid] = b1[tid]; sb2[tid] = b2[tid]; }
    __syncthreads();

    const int t4 = tid & 3;
    const int i = blockIdx.x * 64 + (tid >> 2);

    LOAD_HI(hin + i * HPS);
    (void)sqi;
    float ci[GH];
#pragma unroll
    for (int c = 0; c < GH; ++c) {
        float s = sb1[c];
#pragma unroll
        for (int d = 0; d < GH; ++d) s = fmaf(hi[d], sW1[d*GH+c], s);
        ci[c] = s;
    }
    float acc[GH];
#pragma unroll
    for (int c = 0; c < GH; ++c) acc[c] = 0.f;

    const int4 jj = *(const int4*)(idx + i*GK + t4*4);
    const int js[4] = { jj.x, jj.y, jj.z, jj.w };
#pragma unroll
    for (int nn = 0; nn < 4; ++nn) {
        const int j = js[nn];
        float dj[GH];
        {
            const float* hv = hin + j * HPS;
            float4 A = *(const float4*)(hv + 0);
            float4 B = *(const float4*)(hv + 4);
            float4 C = *(const float4*)(hv + 8);
            float4 D = *(const float4*)(hv + 12);
            dj[0]=A.x-hi[0]; dj[1]=A.y-hi[1]; dj[2]=A.z-hi[2]; dj[3]=A.w-hi[3];
            dj[4]=B.x-hi[4]; dj[5]=B.y-hi[5]; dj[6]=B.z-hi[6]; dj[7]=B.w-hi[7];
            dj[8]=C.x-hi[8]; dj[9]=C.y-hi[9]; dj[10]=C.z-hi[10]; dj[11]=C.w-hi[11];
            dj[12]=D.x-hi[12]; dj[13]=D.y-hi[13]; dj[14]=D.z-hi[14]; dj[15]=D.w-hi[15];
        }
        float msg[GH];
#pragma unroll
        for (int c = 0; c < GH; ++c) {
            float s = ci[c];
#pragma unroll
            for (int d = 0; d < GH; ++d) s = fmaf(dj[d], sW1[(GH+d)*GH+c], s);
            msg[c] = fmaxf(s, 0.f);
        }
#pragma unroll
        for (int c2 = 0; c2 < GH; ++c2) {
            float s = acc[c2];
#pragma unroll
            for (int c = 0; c < GH; ++c) s = fmaf(msg[c], sW2[c*GH+c2], s);
            acc[c2] = s;
        }
    }
#pragma unroll
    for (int c = 0; c < GH; ++c) {
        acc[c] += __shfl_xor(acc[c], 1);
        acc[c] += __shfl_xor(acc[c], 2);
    }
    if (t4 == 0) {
        float* orow = hout + i * HPS;
        float sq = 0.f;
#pragma unroll
        for (int c = 0; c < GH; ++c) {
            float v = acc[c] * (1.f/16.f) + sb2[c];
            orow[c] = v;
            sq = fmaf(v, v, sq);
        }
        orow[16] = sq;
    }
}

// ---------------------------------------------------------------------------
__global__ __launch_bounds__(256) void out_kernel(
    const float* __restrict__ hbase, const float* __restrict__ W,
    const float* __restrict__ b, void* __restrict__ out,
    const int* __restrict__ flag)
{
    int i = blockIdx.x * 256 + threadIdx.x;
    float a0 = b[0], a1 = b[1], a2 = b[2];
#pragma unroll
    for (int l = 0; l < GL; ++l) {
        const float* hp = hbase + l * GN * HPS + i * HPS;
#pragma unroll
        for (int c = 0; c < GH; ++c) {
            const float v = hp[c];
            const float* wr = W + (l * GH + c) * 3;
            a0 = fmaf(v, wr[0], a0);
            a1 = fmaf(v, wr[1], a1);
            a2 = fmaf(v, wr[2], a2);
        }
    }
    if (*flag) {
        __hip_bfloat16* o = (__hip_bfloat16*)out;
        o[i*3+0] = __float2bfloat16(a0);
        o[i*3+1] = __float2bfloat16(a1);
        o[i*3+2] = __float2bfloat16(a2);
    } else {
        float* o = (float*)out;
        o[i*3+0] = a0; o[i*3+1] = a1; o[i*3+2] = a2;
    }
}

// ---------------------------------------------------------------------------
extern "C" void kernel_launch(void* const* d_in, const int* in_sizes, int n_in,
                              void* d_out, int out_size, void* d_ws, size_t ws_size,
                              hipStream_t stream)
{
    float* wsf  = (float*)d_ws;
    int* idxb   = (int*)(wsf + OFF_IDX);
    int* flagsb = (int*)(wsf + OFF_FLAGS);
    int* dflag  = (int*)(wsf + OFF_DFLAG);

    detect_kernel<<<1, 64, 0, stream>>>((const unsigned short*)d_in[0], dflag);

    const int segoff[9] = {OFF_XF, OFF_EMBW, OFF_EMBB, OFF_W1, OFF_B1,
                           OFF_W2, OFF_B2, OFF_OW, OFF_OB};
    const int segn[9]   = {GN*3, 3*GH, GH, GL*2*GH*GH, GL*GH,
                           GL*GH*GH, GL*GH, GL*GH*3, 3};
    for (int s = 0; s < 9; ++s)
        convert_kernel<<<(segn[s] + 255)/256, 256, 0, stream>>>(
            d_in[s], wsf + segoff[s], segn[s], dflag);

    embed_kernel<<<GN/256, 256, 0, stream>>>(
        wsf + OFF_XF, wsf + OFF_EMBW, wsf + OFF_EMBB, wsf + OFF_H);

    for (int l = 0; l < GL; ++l) {
        const float* hin = wsf + OFF_H + l*GN*HPS;
        float* hout      = wsf + OFF_H + (l+1)*GN*HPS;
        knn6_kernel<<<GN/RPB, NTHR, 0, stream>>>(hin, idxb, flagsb);
        rescue_kernel<<<GN/RPB, 64, 0, stream>>>(hin, flagsb, idxb);
        edgeconv_kernel<<<GN/64, 256, 0, stream>>>(hin, idxb,
            wsf + OFF_W1 + l*2*GH*GH, wsf + OFF_B1 + l*GH,
            wsf + OFF_W2 + l*GH*GH,  wsf + OFF_B2 + l*GH, hout);
    }

    out_kernel<<<GN/256, 256, 0, stream>>>(
        wsf + OFF_H + GN*HPS, wsf + OFF_OW, wsf + OFF_OB, d_out, dflag);
}